// Round 13
// baseline (419.339 us; speedup 1.0000x reference)
//
#include <hip/hip_runtime.h>
#include <hip/hip_bf16.h>
#include <math.h>

#define BT 16384
#define DDIM 1024
#define NEXP 16
#define HDIM 2048
#define CAP 1280
#define APITCH 72

typedef __bf16 bf16x8 __attribute__((ext_vector_type(8)));
typedef float f32x4 __attribute__((ext_vector_type(4)));

__device__ __forceinline__ unsigned short f2bf(float f) {
  unsigned u = __float_as_uint(f);
  u += 0x7FFFu + ((u >> 16) & 1u);
  return (unsigned short)(u >> 16);
}

// HW packed fp32->bf16 (RNE, identical to f2bf): dst.lo=cvt(a), dst.hi=cvt(b)
__device__ __forceinline__ unsigned cvt_pk_bf16(float a, float b) {
  unsigned r;
  asm("v_cvt_pk_bf16_f32 %0, %1, %2" : "=v"(r) : "v"(a), "v"(b));
  return r;
}

// gelu(tanh approx) == v * sigmoid(2z); hardware v_exp_f32 path.
__device__ __forceinline__ float fast_gelu(float v) {
  float z = 0.7978845608028654f * (v + 0.044715f * v * v * v);
  return v / (1.0f + __expf(-2.0f * z));
}

#define GLD16(g, l)                                                        \
  __builtin_amdgcn_global_load_lds(                                        \
      (const __attribute__((address_space(1))) unsigned int*)(g),          \
      (__attribute__((address_space(3))) unsigned int*)(l), 16, 0, 0)

// Raw barrier without the vmcnt(0) drain __syncthreads would emit.
#define RAW_BARRIER()                          \
  {                                            \
    __builtin_amdgcn_sched_barrier(0);         \
    __builtin_amdgcn_s_barrier();              \
    __builtin_amdgcn_sched_barrier(0);         \
  }

__global__ void zero_meta_kernel(int* p) {
  int i = threadIdx.x;
  if (i < 32) p[i] = 0;  // counts[16] + m_sel[16]
}

// ---------------- gate: 64 tokens/block; thread = (token, expert-quad) ------
__global__ __launch_bounds__(256) void gate_kernel(
    const float* __restrict__ x, const float* __restrict__ Wg,
    int* __restrict__ e, float* __restrict__ v, int* __restrict__ counts,
    unsigned short* __restrict__ xb, int* __restrict__ flags) {
  __shared__ float wgt[NEXP][DDIM];   // 64KB
  __shared__ float xt[64][68];        // 17.4KB
  __shared__ double lg[64][NEXP];     // 8KB
  __shared__ int hcnt[NEXP];
  int tid = threadIdx.x;
  int t0 = blockIdx.x * 64;
  if (tid < NEXP) hcnt[tid] = 0;
  if (tid < 64) flags[t0 + tid] = 0;
  for (int i = tid; i < DDIM * NEXP / 4; i += 256) {
    int idx = i * 4;
    int d = idx >> 4, n = idx & 15;
    float4 w = *(const float4*)(Wg + idx);
    wgt[n + 0][d] = w.x; wgt[n + 1][d] = w.y;
    wgt[n + 2][d] = w.z; wgt[n + 3][d] = w.w;
  }
  int t = tid & 63, g = tid >> 6;
  double acc[4] = {0.0, 0.0, 0.0, 0.0};
  int sr = tid >> 4;
  int sc = (tid & 15) * 4;
  for (int ch = 0; ch < 16; ++ch) {
    __syncthreads();
#pragma unroll
    for (int i = 0; i < 4; ++i) {
      int r = sr + i * 16;
      float4 xv = *(const float4*)(x + (size_t)(t0 + r) * DDIM + ch * 64 + sc);
      xt[r][sc + 0] = xv.x; xt[r][sc + 1] = xv.y;
      xt[r][sc + 2] = xv.z; xt[r][sc + 3] = xv.w;
      if (xb) {
        unsigned p0 = cvt_pk_bf16(xv.x, xv.y);
        unsigned p1 = cvt_pk_bf16(xv.z, xv.w);
        *(uint2*)(xb + (size_t)(t0 + r) * DDIM + ch * 64 + sc) = make_uint2(p0, p1);
      }
    }
    __syncthreads();
#pragma unroll
    for (int d4 = 0; d4 < 16; ++d4) {
      float4 xv = *(const float4*)(&xt[t][d4 * 4]);
#pragma unroll
      for (int j = 0; j < 4; ++j) {
        float4 wv = *(const float4*)(&wgt[4 * g + j][ch * 64 + d4 * 4]);
        acc[j] += (double)xv.x * (double)wv.x + (double)xv.y * (double)wv.y +
                  (double)xv.z * (double)wv.z + (double)xv.w * (double)wv.w;
      }
    }
  }
#pragma unroll
  for (int j = 0; j < 4; ++j) lg[t][4 * g + j] = acc[j];
  __syncthreads();
  if (tid < 64) {
    double mx = lg[tid][0]; int bi = 0;
#pragma unroll
    for (int n = 1; n < NEXP; ++n)
      if (lg[tid][n] > mx) { mx = lg[tid][n]; bi = n; }
    double s = 0.0;
#pragma unroll
    for (int n = 0; n < NEXP; ++n) s += exp(lg[tid][n] - mx);
    e[t0 + tid] = bi;
    v[t0 + tid] = (float)(1.0 / s);
    atomicAdd(&hcnt[bi], 1);
  }
  __syncthreads();
  if (tid < NEXP && hcnt[tid] > 0) atomicAdd(&counts[tid], hcnt[tid]);
}

// ------- prep: blocks 0..15 = select (R9 semantics); 16.. = transpose -------
__global__ __launch_bounds__(256) void prep_kernel(
    const float* __restrict__ W1, const float* __restrict__ W2,
    unsigned short* __restrict__ w1t, unsigned short* __restrict__ w2t,
    const int* __restrict__ e, const float* __restrict__ v,
    const int* __restrict__ counts, int* __restrict__ m_sel,
    int* __restrict__ lists, int* __restrict__ flags) {
  __shared__ float tile[64][65];
  __shared__ int pos;
  __shared__ int scnt;
  int bid = blockIdx.x;
  int tid = threadIdx.x;
  if (bid < NEXP) {
    int n = bid;
    int cnt = counts[n];
    if (tid == 0) pos = 0;
    __syncthreads();
    if (cnt <= CAP) {
      for (int t = tid; t < BT; t += 256) {
        if (e[t] == n) {
          int p = atomicAdd(&pos, 1);
          lists[n * CAP + p] = t;
          flags[t] = 1;
        }
      }
      __syncthreads();
      if (tid == 0) m_sel[n] = pos;
    } else {
      unsigned lo = 0u, hi = 0x7F800000u;
      while (hi - lo > 1u) {
        unsigned mid = lo + ((hi - lo) >> 1);
        if (tid == 0) scnt = 0;
        __syncthreads();
        int c = 0;
        for (int t = tid; t < BT; t += 256)
          if (e[t] == n && __float_as_uint(v[t]) >= mid) c++;
        atomicAdd(&scnt, c);
        __syncthreads();
        int tot = scnt;
        __syncthreads();
        if (tot >= CAP) lo = mid; else hi = mid;
      }
      for (int t = tid; t < BT; t += 256) {
        if (e[t] == n && __float_as_uint(v[t]) > lo) {
          int p = atomicAdd(&pos, 1);
          lists[n * CAP + p] = t;
          flags[t] = 1;
        }
      }
      __syncthreads();
      if (tid == 0) {
        int p = pos;
        for (int t = 0; t < BT && p < CAP; ++t) {
          if (e[t] == n && __float_as_uint(v[t]) == lo) {
            lists[n * CAP + p] = t; flags[t] = 1; ++p;
          }
        }
        m_sel[n] = p;
      }
    }
    return;
  }
  int b = bid - NEXP;
  const float* in;
  unsigned short* outp;
  int R, C, n, bx, by;
  if (b < 8192) {
    in = W1; outp = w1t; R = DDIM; C = HDIM;
    n = b >> 9; int rem = b & 511; by = rem >> 5; bx = rem & 31;
  } else {
    b -= 8192;
    in = W2; outp = w2t; R = HDIM; C = DDIM;
    n = b >> 9; int rem = b & 511; by = rem >> 4; bx = rem & 15;
  }
  const float* src = in + (size_t)n * R * C;
  unsigned short* dst = outp + (size_t)n * R * C;
  int r0 = by * 64, c0 = bx * 64;
  int lr = tid >> 2, lq = tid & 3;
#pragma unroll
  for (int i = 0; i < 4; ++i) {
    float4 vv = *(const float4*)(src + (size_t)(r0 + lr) * C + c0 + i * 16 + lq * 4);
    *(float4*)(&tile[lr][i * 16 + lq * 4]) = vv;
  }
  __syncthreads();
  int oc2 = tid >> 3, lq2 = tid & 7;
#pragma unroll
  for (int p = 0; p < 2; ++p) {
    int oc = p * 32 + oc2;
    int rb = lq2 * 8;
    uint4 pk;
    pk.x = cvt_pk_bf16(tile[rb + 0][oc], tile[rb + 1][oc]);
    pk.y = cvt_pk_bf16(tile[rb + 2][oc], tile[rb + 3][oc]);
    pk.z = cvt_pk_bf16(tile[rb + 4][oc], tile[rb + 5][oc]);
    pk.w = cvt_pk_bf16(tile[rb + 6][oc], tile[rb + 7][oc]);
    *(uint4*)(dst + (size_t)(c0 + oc) * R + r0 + rb) = pk;
  }
}

// ======================= FAST PATH (bf16 pre-converted) =====================
// R13: 128x128 tile, BK=32, THREE-buffer ring (48KB LDS -> 3 blocks/CU,
// 12 waves), ONE barrier + one vm-wait per iter:
//   iter t: stage(t+2 -> buf[(t+2)%3]); ds_read frags(buf[t%3]); MFMA;
//           vmcnt(4) [my stage(t+1) landed]; lgkm0; BARRIER.
// Hazards: stage(t+2) overwrites buf[(t-1)%3] whose reads finished before the
// end-of-(t-1) barrier; buf[t] globally ready via end-of-(t-1) vm-wait+barrier.
// Granule swizzle for 64B rows: g_phys = g ^ ((row>>1)&3), both sides (rule 21).
// Accumulation order identical to BK=64 version (bit-exact).

__global__ __launch_bounds__(256) void ffn1_fast(
    const unsigned short* __restrict__ xb, const unsigned short* __restrict__ w1t,
    const float* __restrict__ b1, const int* __restrict__ m_sel,
    const int* __restrict__ lists, unsigned short* __restrict__ H) {
  __shared__ __align__(16) unsigned short As[3][128 * 32];  // 24KB
  __shared__ __align__(16) unsigned short Bs[3][128 * 32];  // 24KB
  const int NWG = NEXP * 10 * 16;  // 2560
  const int NT = DDIM / 32;        // 32
  int bid = blockIdx.x;
  int lid = (bid & 7) * (NWG / 8) + (bid >> 3);
  int n = lid / 160;
  int rem = lid - n * 160;
  int mt = rem >> 4, ht = rem & 15;
  int M = m_sel[n];
  if (mt * 128 >= M) return;
  int tid = threadIdx.x;
  int lane = tid & 63, wid = tid >> 6;
  int wr = (wid >> 1) * 64, wc = (wid & 1) * 64;
  int rbase = tid >> 2;  // 0..63
  int c4 = tid & 3;
  const char* xbase = (const char*)xb;
  const char* bbase = (const char*)w1t + (((size_t)n * HDIM + (size_t)ht * 128) * DDIM) * 2;
  unsigned asrc[2], bsrc[2], ldsoff[2];
#pragma unroll
  for (int j = 0; j < 2; ++j) {
    int row = j * 64 + rbase;
    int sg = (c4 ^ ((row >> 1) & 3)) * 16;
    int s = mt * 128 + row;
    int tok = lists[n * CAP + (s < M ? s : 0)];
    asrc[j] = (unsigned)tok * 2048u + sg;
    bsrc[j] = (unsigned)row * 2048u + sg;
    ldsoff[j] = j * 4096 + wid * 1024;
  }
  unsigned aoff[4], boff[4];
#pragma unroll
  for (int mi = 0; mi < 4; ++mi) {
    int row = wr + mi * 16 + (lane & 15);
    aoff[mi] = row * 64 + ((((lane >> 4) ^ ((row >> 1) & 3))) << 4);
  }
#pragma unroll
  for (int ni = 0; ni < 4; ++ni) {
    int row = wc + ni * 16 + (lane & 15);
    boff[ni] = row * 64 + ((((lane >> 4) ^ ((row >> 1) & 3))) << 4);
  }
  f32x4 acc[4][4] = {};
#define STAGE1(buf, kt)                                                       \
  {                                                                           \
    unsigned ko = (unsigned)(kt) * 64u;                                       \
    _Pragma("unroll") for (int j = 0; j < 2; ++j) {                           \
      GLD16(xbase + (size_t)(asrc[j] + ko), (char*)As[buf] + ldsoff[j]);      \
      GLD16(bbase + (size_t)(bsrc[j] + ko), (char*)Bs[buf] + ldsoff[j]);      \
    }                                                                         \
  }
  STAGE1(0, 0);
  STAGE1(1, 1);
  asm volatile("s_waitcnt vmcnt(4)" ::: "memory");
  RAW_BARRIER();
  int cur = 0;
  for (int t = 0; t < NT; ++t) {
    int b2 = cur + 2; if (b2 >= 3) b2 -= 3;
    if (t + 2 < NT) STAGE1(b2, t + 2);
    bf16x8 af[4], bfv[4];
#pragma unroll
    for (int mi = 0; mi < 4; ++mi)
      af[mi] = *(const bf16x8*)((const char*)As[cur] + aoff[mi]);
#pragma unroll
    for (int ni = 0; ni < 4; ++ni)
      bfv[ni] = *(const bf16x8*)((const char*)Bs[cur] + boff[ni]);
    __builtin_amdgcn_s_setprio(1);
#pragma unroll
    for (int mi = 0; mi < 4; ++mi)
#pragma unroll
      for (int ni = 0; ni < 4; ++ni)
        acc[mi][ni] = __builtin_amdgcn_mfma_f32_16x16x32_bf16(af[mi], bfv[ni], acc[mi][ni], 0, 0, 0);
    __builtin_amdgcn_s_setprio(0);
    if (t < NT - 1) {
      if (t + 2 < NT) asm volatile("s_waitcnt vmcnt(4)" ::: "memory");
      else            asm volatile("s_waitcnt vmcnt(0)" ::: "memory");
      asm volatile("s_waitcnt lgkmcnt(0)" ::: "memory");
      RAW_BARRIER();
    }
    cur = cur + 1; if (cur >= 3) cur -= 3;
  }
  int rq = (lane >> 4) * 4;
#pragma unroll
  for (int ni = 0; ni < 4; ++ni) {
    int h = ht * 128 + wc + ni * 16 + (lane & 15);
    float bias = b1[n * HDIM + h];
#pragma unroll
    for (int mi = 0; mi < 4; ++mi) {
#pragma unroll
      for (int q = 0; q < 4; ++q) {
        int lr = wr + mi * 16 + rq + q;
        float val = acc[mi][ni][q] + bias;
        H[((size_t)n * CAP + mt * 128 + lr) * HDIM + h] = f2bf(fast_gelu(val));
      }
    }
  }
}

__global__ __launch_bounds__(256) void ffn2_fast(
    const unsigned short* __restrict__ H, const unsigned short* __restrict__ w2t,
    const float* __restrict__ b2, const int* __restrict__ m_sel,
    const int* __restrict__ lists, float* __restrict__ out) {
  __shared__ __align__(16) unsigned short As[3][128 * 32];
  __shared__ __align__(16) unsigned short Bs[3][128 * 32];
  const int NWG = NEXP * 10 * 8;  // 1280
  const int NT = HDIM / 32;       // 64
  int bid = blockIdx.x;
  int tid = threadIdx.x;
  int lid = (bid & 7) * (NWG / 8) + (bid >> 3);
  int n = lid / 80;
  int rem = lid - n * 80;
  int mt = rem >> 3, dt = rem & 7;
  int M = m_sel[n];
  if (mt * 128 >= M) return;
  int lane = tid & 63, wid = tid >> 6;
  int wr = (wid >> 1) * 64, wc = (wid & 1) * 64;
  int rbase = tid >> 2;
  int c4 = tid & 3;
  const char* abase = (const char*)H + (((size_t)n * CAP + (size_t)mt * 128) * HDIM) * 2;
  const char* bbase = (const char*)w2t + (((size_t)n * DDIM + (size_t)dt * 128) * HDIM) * 2;
  unsigned asrc[2], bsrc[2], ldsoff[2];
#pragma unroll
  for (int j = 0; j < 2; ++j) {
    int row = j * 64 + rbase;
    int sg = (c4 ^ ((row >> 1) & 3)) * 16;
    asrc[j] = (unsigned)row * 4096u + sg;
    bsrc[j] = (unsigned)row * 4096u + sg;
    ldsoff[j] = j * 4096 + wid * 1024;
  }
  unsigned aoff[4], boff[4];
#pragma unroll
  for (int mi = 0; mi < 4; ++mi) {
    int row = wr + mi * 16 + (lane & 15);
    aoff[mi] = row * 64 + ((((lane >> 4) ^ ((row >> 1) & 3))) << 4);
  }
#pragma unroll
  for (int ni = 0; ni < 4; ++ni) {
    int row = wc + ni * 16 + (lane & 15);
    boff[ni] = row * 64 + ((((lane >> 4) ^ ((row >> 1) & 3))) << 4);
  }
  f32x4 acc[4][4] = {};
#define STAGE2(buf, kt)                                                       \
  {                                                                           \
    unsigned ko = (unsigned)(kt) * 64u;                                       \
    _Pragma("unroll") for (int j = 0; j < 2; ++j) {                           \
      GLD16(abase + (size_t)(asrc[j] + ko), (char*)As[buf] + ldsoff[j]);      \
      GLD16(bbase + (size_t)(bsrc[j] + ko), (char*)Bs[buf] + ldsoff[j]);      \
    }                                                                         \
  }
  STAGE2(0, 0);
  STAGE2(1, 1);
  asm volatile("s_waitcnt vmcnt(4)" ::: "memory");
  RAW_BARRIER();
  int cur = 0;
  for (int t = 0; t < NT; ++t) {
    int b2 = cur + 2; if (b2 >= 3) b2 -= 3;
    if (t + 2 < NT) STAGE2(b2, t + 2);
    bf16x8 af[4], bfv[4];
#pragma unroll
    for (int mi = 0; mi < 4; ++mi)
      af[mi] = *(const bf16x8*)((const char*)As[cur] + aoff[mi]);
#pragma unroll
    for (int ni = 0; ni < 4; ++ni)
      bfv[ni] = *(const bf16x8*)((const char*)Bs[cur] + boff[ni]);
    __builtin_amdgcn_s_setprio(1);
#pragma unroll
    for (int mi = 0; mi < 4; ++mi)
#pragma unroll
      for (int ni = 0; ni < 4; ++ni)
        acc[mi][ni] = __builtin_amdgcn_mfma_f32_16x16x32_bf16(af[mi], bfv[ni], acc[mi][ni], 0, 0, 0);
    __builtin_amdgcn_s_setprio(0);
    if (t < NT - 1) {
      if (t + 2 < NT) asm volatile("s_waitcnt vmcnt(4)" ::: "memory");
      else            asm volatile("s_waitcnt vmcnt(0)" ::: "memory");
      asm volatile("s_waitcnt lgkmcnt(0)" ::: "memory");
      RAW_BARRIER();
    }
    cur = cur + 1; if (cur >= 3) cur -= 3;
  }
  int rq = (lane >> 4) * 4;
  float bias[4];
#pragma unroll
  for (int ni = 0; ni < 4; ++ni)
    bias[ni] = b2[n * DDIM + dt * 128 + wc + ni * 16 + (lane & 15)];
#pragma unroll
  for (int mi = 0; mi < 4; ++mi) {
#pragma unroll
    for (int q = 0; q < 4; ++q) {
      int lr = wr + mi * 16 + rq + q;
      int s = mt * 128 + lr;
      if (s < M) {
        int tok = lists[n * CAP + s];
#pragma unroll
        for (int ni = 0; ni < 4; ++ni) {
          int dcol = dt * 128 + wc + ni * 16 + (lane & 15);
          out[(size_t)tok * DDIM + dcol] = acc[mi][ni][q] + bias[ni];
        }
      }
    }
  }
}

// ======================= SLOW PATH (ws fallback) ============================
__global__ void select_kernel(const int* __restrict__ e, const float* __restrict__ v,
                              const int* __restrict__ counts, int* __restrict__ m_sel,
                              int* __restrict__ lists, int* __restrict__ flags) {
  int n = blockIdx.x;
  int tid = threadIdx.x;
  int cnt = counts[n];
  __shared__ int pos;
  if (tid == 0) pos = 0;
  __syncthreads();
  if (cnt <= CAP) {
    for (int t = tid; t < BT; t += 256) {
      if (e[t] == n) {
        int p = atomicAdd(&pos, 1);
        lists[n * CAP + p] = t;
        flags[t] = 1;
      }
    }
    __syncthreads();
    if (tid == 0) m_sel[n] = pos;
  } else {
    __shared__ int scnt;
    unsigned lo = 0u, hi = 0x7F800000u;
    while (hi - lo > 1u) {
      unsigned mid = lo + ((hi - lo) >> 1);
      if (tid == 0) scnt = 0;
      __syncthreads();
      int c = 0;
      for (int t = tid; t < BT; t += 256)
        if (e[t] == n && __float_as_uint(v[t]) >= mid) c++;
      atomicAdd(&scnt, c);
      __syncthreads();
      int tot = scnt;
      __syncthreads();
      if (tot >= CAP) lo = mid; else hi = mid;
    }
    for (int t = tid; t < BT; t += 256) {
      if (e[t] == n && __float_as_uint(v[t]) > lo) {
        int p = atomicAdd(&pos, 1);
        lists[n * CAP + p] = t;
        flags[t] = 1;
      }
    }
    __syncthreads();
    if (tid == 0) {
      int p = pos;
      for (int t = 0; t < BT && p < CAP; ++t) {
        if (e[t] == n && __float_as_uint(v[t]) == lo) {
          lists[n * CAP + p] = t; flags[t] = 1; ++p;
        }
      }
      m_sel[n] = p;
    }
  }
}

__global__ __launch_bounds__(256) void ffn1_slow(
    const float* __restrict__ x, const float* __restrict__ W1, const float* __restrict__ b1,
    const int* __restrict__ m_sel, const int* __restrict__ lists,
    unsigned short* __restrict__ H) {
  __shared__ unsigned short Al[128 * APITCH];
  __shared__ unsigned short Bl[128 * APITCH];
  __shared__ int rows[128];
  int n = blockIdx.z, mt = blockIdx.y, ht = blockIdx.x;
  int M = m_sel[n];
  if (mt * 128 >= M) return;
  int tid = threadIdx.x;
  if (tid < 128) {
    int s = mt * 128 + tid;
    rows[tid] = lists[n * CAP + (s < M ? s : 0)];
  }
  __syncthreads();
  f32x4 acc[4][4] = {};
  int lane = tid & 63;
  int wid = tid >> 6;
  int wr = (wid >> 1) * 64, wc = (wid & 1) * 64;
  int ar = tid >> 4, ac = (tid & 15) * 4;
  int bh = tid & 127, bk8 = (tid >> 7) * 8;
  const size_t w1base = (size_t)n * DDIM * HDIM + (size_t)ht * 128;
  for (int kt = 0; kt < DDIM / 64; ++kt) {
#pragma unroll
    for (int i = 0; i < 8; ++i) {
      int r = ar + i * 16;
      float4 xv = *(const float4*)(x + (size_t)rows[r] * DDIM + kt * 64 + ac);
      unsigned plo = (unsigned)f2bf(xv.x) | ((unsigned)f2bf(xv.y) << 16);
      unsigned phi = (unsigned)f2bf(xv.z) | ((unsigned)f2bf(xv.w) << 16);
      *(uint2*)(&Al[r * APITCH + ac]) = make_uint2(plo, phi);
    }
#pragma unroll
    for (int i = 0; i < 4; ++i) {
      int k0 = bk8 + i * 16;
      const float* wp = W1 + w1base + (size_t)(kt * 64 + k0) * HDIM + bh;
      uint4 pk;
      pk.x = (unsigned)f2bf(wp[0]) | ((unsigned)f2bf(wp[HDIM]) << 16);
      pk.y = (unsigned)f2bf(wp[2 * HDIM]) | ((unsigned)f2bf(wp[3 * HDIM]) << 16);
      pk.z = (unsigned)f2bf(wp[4 * HDIM]) | ((unsigned)f2bf(wp[5 * HDIM]) << 16);
      pk.w = (unsigned)f2bf(wp[6 * HDIM]) | ((unsigned)f2bf(wp[7 * HDIM]) << 16);
      *(uint4*)(&Bl[bh * APITCH + k0]) = pk;
    }
    __syncthreads();
#pragma unroll
    for (int kk = 0; kk < 2; ++kk) {
      bf16x8 af[4], bfr[4];
#pragma unroll
      for (int mi = 0; mi < 4; ++mi)
        af[mi] = *(const bf16x8*)(&Al[(wr + mi * 16 + (lane & 15)) * APITCH + kk * 32 + (lane >> 4) * 8]);
#pragma unroll
      for (int ni = 0; ni < 4; ++ni)
        bfr[ni] = *(const bf16x8*)(&Bl[(wc + ni * 16 + (lane & 15)) * APITCH + kk * 32 + (lane >> 4) * 8]);
#pragma unroll
      for (int mi = 0; mi < 4; ++mi)
#pragma unroll
        for (int ni = 0; ni < 4; ++ni)
          acc[mi][ni] = __builtin_amdgcn_mfma_f32_16x16x32_bf16(af[mi], bfr[ni], acc[mi][ni], 0, 0, 0);
    }
    __syncthreads();
  }
  int rq = (lane >> 4) * 4;
#pragma unroll
  for (int ni = 0; ni < 4; ++ni) {
    int h = ht * 128 + wc + ni * 16 + (lane & 15);
    float bias = b1[n * HDIM + h];
#pragma unroll
    for (int mi = 0; mi < 4; ++mi) {
#pragma unroll
      for (int q = 0; q < 4; ++q) {
        int lr = wr + mi * 16 + rq + q;
        float val = acc[mi][ni][q] + bias;
        H[((size_t)n * CAP + mt * 128 + lr) * HDIM + h] = f2bf(fast_gelu(val));
      }
    }
  }
}

__global__ __launch_bounds__(256) void ffn2_slow(
    const unsigned short* __restrict__ H, const float* __restrict__ W2, const float* __restrict__ b2,
    const int* __restrict__ m_sel, const int* __restrict__ lists,
    float* __restrict__ out) {
  __shared__ unsigned short Al[128 * APITCH];
  __shared__ unsigned short Bl[128 * APITCH];
  __shared__ int rows[128];
  int n = blockIdx.z, mt = blockIdx.y, dt = blockIdx.x;
  int M = m_sel[n];
  if (mt * 128 >= M) return;
  int tid = threadIdx.x;
  if (tid < 128) {
    int s = mt * 128 + tid;
    rows[tid] = lists[n * CAP + (s < M ? s : 0)];
  }
  __syncthreads();
  f32x4 acc[4][4] = {};
  int lane = tid & 63;
  int wid = tid >> 6;
  int wr = (wid >> 1) * 64, wc = (wid & 1) * 64;
  int ar2 = tid >> 1, ak8 = (tid & 1) * 8;
  int bh = tid & 127, bk8 = (tid >> 7) * 8;
  const size_t hbase = ((size_t)n * CAP + (size_t)mt * 128) * HDIM;
  const size_t w2base = (size_t)n * HDIM * DDIM + (size_t)dt * 128;
  for (int kt = 0; kt < HDIM / 64; ++kt) {
#pragma unroll
    for (int i = 0; i < 4; ++i) {
      int k0 = ak8 + i * 16;
      uint4 hv = *(const uint4*)(H + hbase + (size_t)ar2 * HDIM + kt * 64 + k0);
      *(uint4*)(&Al[ar2 * APITCH + k0]) = hv;
    }
#pragma unroll
    for (int i = 0; i < 4; ++i) {
      int k0 = bk8 + i * 16;
      const float* wp = W2 + w2base + (size_t)(kt * 64 + k0) * DDIM + bh;
      uint4 pk;
      pk.x = (unsigned)f2bf(wp[0]) | ((unsigned)f2bf(wp[DDIM]) << 16);
      pk.y = (unsigned)f2bf(wp[2 * DDIM]) | ((unsigned)f2bf(wp[3 * DDIM]) << 16);
      pk.z = (unsigned)f2bf(wp[4 * DDIM]) | ((unsigned)f2bf(wp[5 * DDIM]) << 16);
      pk.w = (unsigned)f2bf(wp[6 * DDIM]) | ((unsigned)f2bf(wp[7 * DDIM]) << 16);
      *(uint4*)(&Bl[bh * APITCH + k0]) = pk;
    }
    __syncthreads();
#pragma unroll
    for (int kk = 0; kk < 2; ++kk) {
      bf16x8 af[4], bfr[4];
#pragma unroll
      for (int mi = 0; mi < 4; ++mi)
        af[mi] = *(const bf16x8*)(&Al[(wr + mi * 16 + (lane & 15)) * APITCH + kk * 32 + (lane >> 4) * 8]);
#pragma unroll
      for (int ni = 0; ni < 4; ++ni)
        bfr[ni] = *(const bf16x8*)(&Bl[(wc + ni * 16 + (lane & 15)) * APITCH + kk * 32 + (lane >> 4) * 8]);
#pragma unroll
      for (int mi = 0; mi < 4; ++mi)
#pragma unroll
        for (int ni = 0; ni < 4; ++ni)
          acc[mi][ni] = __builtin_amdgcn_mfma_f32_16x16x32_bf16(af[mi], bfr[ni], acc[mi][ni], 0, 0, 0);
    }
    __syncthreads();
  }
  int rq = (lane >> 4) * 4;
#pragma unroll
  for (int mi = 0; mi < 4; ++mi) {
#pragma unroll
    for (int q = 0; q < 4; ++q) {
      int lr = wr + mi * 16 + rq + q;
      int s = mt * 128 + lr;
      if (s < M) {
        int tok = rows[lr];
#pragma unroll
        for (int ni = 0; ni < 4; ++ni) {
          int dcol = dt * 128 + wc + ni * 16 + (lane & 15);
          out[(size_t)tok * DDIM + dcol] = acc[mi][ni][q] + b2[n * DDIM + dcol];
        }
      }
    }
  }
}

// ---------------- passthrough: one wave per row, 1024 blocks ----------------
__global__ __launch_bounds__(256) void passthrough_kernel(
    const float* __restrict__ x, const int* __restrict__ flags,
    float* __restrict__ out) {
  int lane = threadIdx.x & 63;
  int w = threadIdx.x >> 6;
  int base = blockIdx.x * 16;
  for (int r = base + w; r < base + 16; r += 4) {
    if (flags[r]) continue;
    const float4* s = (const float4*)(x + (size_t)r * DDIM);
    float4* d = (float4*)(out + (size_t)r * DDIM);
#pragma unroll
    for (int i = 0; i < 4; ++i) d[lane + i * 64] = s[lane + i * 64];
  }
}

extern "C" void kernel_launch(void* const* d_in, const int* in_sizes, int n_in,
                              void* d_out, int out_size, void* d_ws, size_t ws_size,
                              hipStream_t stream) {
  const float* x  = (const float*)d_in[0];
  const float* Wg = (const float*)d_in[1];
  const float* W1 = (const float*)d_in[2];
  const float* b1 = (const float*)d_in[3];
  const float* W2 = (const float*)d_in[4];
  const float* b2 = (const float*)d_in[5];
  float* out = (float*)d_out;
  char* ws = (char*)d_ws;
  int* counts = (int*)ws;
  int* m_sel  = (int*)(ws + 64);
  int* flags  = (int*)(ws + 128);
  int* e      = (int*)(ws + 128 + 4 * BT);
  float* v    = (float*)(ws + 128 + 8 * BT);
  int* lists  = (int*)(ws + 128 + 12 * BT);

  const size_t MB = 1024 * 1024;
  unsigned short* xb  = (unsigned short*)(ws + 1 * MB);
  unsigned short* w1t = (unsigned short*)(ws + 33 * MB);
  unsigned short* w2t = (unsigned short*)(ws + 97 * MB);
  unsigned short* Hf  = (unsigned short*)(ws + 161 * MB);
  bool fast = ws_size >= 242 * MB;

  zero_meta_kernel<<<1, 64, 0, stream>>>(counts);
  if (fast) {
    gate_kernel<<<BT / 64, 256, 0, stream>>>(x, Wg, e, v, counts, xb, flags);
    prep_kernel<<<NEXP + 16384, 256, 0, stream>>>(W1, W2, w1t, w2t, e, v, counts, m_sel, lists, flags);
    ffn1_fast<<<NEXP * 10 * 16, 256, 0, stream>>>(xb, w1t, b1, m_sel, lists, Hf);
    ffn2_fast<<<NEXP * 10 * 8, 256, 0, stream>>>(Hf, w2t, b2, m_sel, lists, out);
  } else {
    unsigned short* Hs = (unsigned short*)(ws + 1 * MB);
    gate_kernel<<<BT / 64, 256, 0, stream>>>(x, Wg, e, v, counts, (unsigned short*)nullptr, flags);
    select_kernel<<<NEXP, 256, 0, stream>>>(e, v, counts, m_sel, lists, flags);
    ffn1_slow<<<dim3(HDIM / 128, CAP / 128, NEXP), 256, 0, stream>>>(x, W1, b1, m_sel, lists, Hs);
    ffn2_slow<<<dim3(DDIM / 128, CAP / 128, NEXP), 256, 0, stream>>>(Hs, W2, b2, m_sel, lists, out);
  }
  passthrough_kernel<<<BT / 16, 256, 0, stream>>>(x, flags, out);
}

// Round 14
// 395.129 us; speedup vs baseline: 1.0613x; 1.0613x over previous
//
#include <hip/hip_runtime.h>
#include <hip/hip_bf16.h>
#include <math.h>

#define BT 16384
#define DDIM 1024
#define NEXP 16
#define HDIM 2048
#define CAP 1280
#define APITCH 72

typedef __bf16 bf16x8 __attribute__((ext_vector_type(8)));
typedef float f32x4 __attribute__((ext_vector_type(4)));

__device__ __forceinline__ unsigned short f2bf(float f) {
  unsigned u = __float_as_uint(f);
  u += 0x7FFFu + ((u >> 16) & 1u);
  return (unsigned short)(u >> 16);
}

// HW packed fp32->bf16 (RNE, identical to f2bf): dst.lo=cvt(a), dst.hi=cvt(b)
__device__ __forceinline__ unsigned cvt_pk_bf16(float a, float b) {
  unsigned r;
  asm("v_cvt_pk_bf16_f32 %0, %1, %2" : "=v"(r) : "v"(a), "v"(b));
  return r;
}

// gelu(tanh approx) == v * sigmoid(2z); hardware v_exp_f32 path.
__device__ __forceinline__ float fast_gelu(float v) {
  float z = 0.7978845608028654f * (v + 0.044715f * v * v * v);
  return v / (1.0f + __expf(-2.0f * z));
}

#define GLD16(g, l)                                                        \
  __builtin_amdgcn_global_load_lds(                                        \
      (const __attribute__((address_space(1))) unsigned int*)(g),          \
      (__attribute__((address_space(3))) unsigned int*)(l), 16, 0, 0)

// Raw barrier without the vmcnt(0) drain __syncthreads would emit.
#define RAW_BARRIER()                          \
  {                                            \
    __builtin_amdgcn_sched_barrier(0);         \
    __builtin_amdgcn_s_barrier();              \
    __builtin_amdgcn_sched_barrier(0);         \
  }

__global__ void zero_meta_kernel(int* p) {
  int i = threadIdx.x;
  if (i < 32) p[i] = 0;  // counts[16] + m_sel[16]
}

// ======== fused prep: blocks [0,256) = gate (streamed Wg chunks, 30KB LDS);
// ========             blocks [256,..) = W1/W2 transpose+cvt (16.3KB LDS).
// gate and transpose are data-independent; fusing hides gate's 28us under
// the HBM-bound transpose. Gate accumulation order bit-identical to R12.
__global__ __launch_bounds__(256) void prep_kernel(
    const float* __restrict__ x, const float* __restrict__ Wg,
    int* __restrict__ e, float* __restrict__ v, int* __restrict__ counts,
    unsigned short* __restrict__ xb, int* __restrict__ flags,
    const float* __restrict__ W1, const float* __restrict__ W2,
    unsigned short* __restrict__ w1t, unsigned short* __restrict__ w2t) {
  __shared__ __align__(16) char smem[30016];
  int bid = blockIdx.x;
  int tid = threadIdx.x;
  if (bid < 256) {
    // ---------------- gate: 64 tokens/block ----------------
    float* xt = (float*)smem;                       // [64][68]  17408B
    double* lg = (double*)(smem + 17408);           // [64][16]   8192B
    float* wgt_c = (float*)(smem + 25600);          // [16][68]   4352B
    int* hcnt = (int*)(smem + 29952);               // [16]
    int t0 = bid * 64;
    if (tid < NEXP) hcnt[tid] = 0;
    if (tid < 64) flags[t0 + tid] = 0;
    int t = tid & 63, g = tid >> 6;
    double acc[4] = {0.0, 0.0, 0.0, 0.0};
    int sr = tid >> 4;
    int sc = (tid & 15) * 4;
    int wd = tid >> 2, wn = (tid & 3) * 4;
    for (int ch = 0; ch < 16; ++ch) {
      __syncthreads();
#pragma unroll
      for (int i = 0; i < 4; ++i) {
        int r = sr + i * 16;
        float4 xv = *(const float4*)(x + (size_t)(t0 + r) * DDIM + ch * 64 + sc);
        xt[r * 68 + sc + 0] = xv.x; xt[r * 68 + sc + 1] = xv.y;
        xt[r * 68 + sc + 2] = xv.z; xt[r * 68 + sc + 3] = xv.w;
        unsigned p0 = cvt_pk_bf16(xv.x, xv.y);
        unsigned p1 = cvt_pk_bf16(xv.z, xv.w);
        *(uint2*)(xb + (size_t)(t0 + r) * DDIM + ch * 64 + sc) = make_uint2(p0, p1);
      }
      {
        float4 w = *(const float4*)(Wg + ch * 1024 + tid * 4);
        wgt_c[(wn + 0) * 68 + wd] = w.x;
        wgt_c[(wn + 1) * 68 + wd] = w.y;
        wgt_c[(wn + 2) * 68 + wd] = w.z;
        wgt_c[(wn + 3) * 68 + wd] = w.w;
      }
      __syncthreads();
#pragma unroll
      for (int d4 = 0; d4 < 16; ++d4) {
        float4 xv = *(const float4*)(&xt[t * 68 + d4 * 4]);
#pragma unroll
        for (int j = 0; j < 4; ++j) {
          float4 wv = *(const float4*)(&wgt_c[(4 * g + j) * 68 + d4 * 4]);
          acc[j] += (double)xv.x * (double)wv.x + (double)xv.y * (double)wv.y +
                    (double)xv.z * (double)wv.z + (double)xv.w * (double)wv.w;
        }
      }
    }
#pragma unroll
    for (int j = 0; j < 4; ++j) lg[t * 16 + 4 * g + j] = acc[j];
    __syncthreads();
    if (tid < 64) {
      double mx = lg[tid * 16]; int bi = 0;
#pragma unroll
      for (int n = 1; n < NEXP; ++n)
        if (lg[tid * 16 + n] > mx) { mx = lg[tid * 16 + n]; bi = n; }
      double s = 0.0;
#pragma unroll
      for (int n = 0; n < NEXP; ++n) s += exp(lg[tid * 16 + n] - mx);
      e[t0 + tid] = bi;
      v[t0 + tid] = (float)(1.0 / s);
      atomicAdd(&hcnt[bi], 1);
    }
    __syncthreads();
    if (tid < NEXP && hcnt[tid] > 0) atomicAdd(&counts[tid], hcnt[tid]);
    return;
  }
  // ---------------- transpose + fp32->bf16 ----------------
  float* tile = (float*)smem;  // [64][65]
  int b = bid - 256;
  const float* in;
  unsigned short* outp;
  int R, C, n, bx, by;
  if (b < 8192) {  // W1 [n][1024][2048] -> w1t [n][2048][1024]
    in = W1; outp = w1t; R = DDIM; C = HDIM;
    n = b >> 9; int rem = b & 511; by = rem >> 5; bx = rem & 31;
  } else {         // W2 [n][2048][1024] -> w2t [n][1024][2048]
    b -= 8192;
    in = W2; outp = w2t; R = HDIM; C = DDIM;
    n = b >> 9; int rem = b & 511; by = rem >> 4; bx = rem & 15;
  }
  const float* src = in + (size_t)n * R * C;
  unsigned short* dst = outp + (size_t)n * R * C;
  int r0 = by * 64, c0 = bx * 64;
  int lr = tid >> 2, lq = tid & 3;
#pragma unroll
  for (int i = 0; i < 4; ++i) {
    float4 vv = *(const float4*)(src + (size_t)(r0 + lr) * C + c0 + i * 16 + lq * 4);
    *(float4*)(&tile[lr * 65 + i * 16 + lq * 4]) = vv;
  }
  __syncthreads();
  int oc2 = tid >> 3, lq2 = tid & 7;
#pragma unroll
  for (int p = 0; p < 2; ++p) {
    int oc = p * 32 + oc2;
    int rb = lq2 * 8;
    uint4 pk;
    pk.x = cvt_pk_bf16(tile[(rb + 0) * 65 + oc], tile[(rb + 1) * 65 + oc]);
    pk.y = cvt_pk_bf16(tile[(rb + 2) * 65 + oc], tile[(rb + 3) * 65 + oc]);
    pk.z = cvt_pk_bf16(tile[(rb + 4) * 65 + oc], tile[(rb + 5) * 65 + oc]);
    pk.w = cvt_pk_bf16(tile[(rb + 6) * 65 + oc], tile[(rb + 7) * 65 + oc]);
    *(uint4*)(dst + (size_t)(c0 + oc) * R + r0 + rb) = pk;
  }
}

// ---------------- select: per-expert token set under capacity ---------------
__global__ void select_kernel(const int* __restrict__ e, const float* __restrict__ v,
                              const int* __restrict__ counts, int* __restrict__ m_sel,
                              int* __restrict__ lists, int* __restrict__ flags) {
  int n = blockIdx.x;
  int tid = threadIdx.x;
  int cnt = counts[n];
  __shared__ int pos;
  if (tid == 0) pos = 0;
  __syncthreads();
  if (cnt <= CAP) {
    for (int t = tid; t < BT; t += 256) {
      if (e[t] == n) {
        int p = atomicAdd(&pos, 1);
        lists[n * CAP + p] = t;
        flags[t] = 1;
      }
    }
    __syncthreads();
    if (tid == 0) m_sel[n] = pos;
  } else {
    __shared__ int scnt;
    unsigned lo = 0u, hi = 0x7F800000u;
    while (hi - lo > 1u) {
      unsigned mid = lo + ((hi - lo) >> 1);
      if (tid == 0) scnt = 0;
      __syncthreads();
      int c = 0;
      for (int t = tid; t < BT; t += 256)
        if (e[t] == n && __float_as_uint(v[t]) >= mid) c++;
      atomicAdd(&scnt, c);
      __syncthreads();
      int tot = scnt;
      __syncthreads();
      if (tot >= CAP) lo = mid; else hi = mid;
    }
    for (int t = tid; t < BT; t += 256) {
      if (e[t] == n && __float_as_uint(v[t]) > lo) {
        int p = atomicAdd(&pos, 1);
        lists[n * CAP + p] = t;
        flags[t] = 1;
      }
    }
    __syncthreads();
    if (tid == 0) {
      int p = pos;
      for (int t = 0; t < BT && p < CAP; ++t) {
        if (e[t] == n && __float_as_uint(v[t]) == lo) {
          lists[n * CAP + p] = t; flags[t] = 1; ++p;
        }
      }
      m_sel[n] = p;
    }
  }
}

// ---------------- gate (slow path only, resident Wg table) ------------------
__global__ __launch_bounds__(256) void gate_kernel(
    const float* __restrict__ x, const float* __restrict__ Wg,
    int* __restrict__ e, float* __restrict__ v, int* __restrict__ counts,
    unsigned short* __restrict__ xb, int* __restrict__ flags) {
  __shared__ float wgt[NEXP][DDIM];
  __shared__ float xt[64][68];
  __shared__ double lg[64][NEXP];
  __shared__ int hcnt[NEXP];
  int tid = threadIdx.x;
  int t0 = blockIdx.x * 64;
  if (tid < NEXP) hcnt[tid] = 0;
  if (tid < 64) flags[t0 + tid] = 0;
  for (int i = tid; i < DDIM * NEXP / 4; i += 256) {
    int idx = i * 4;
    int d = idx >> 4, n = idx & 15;
    float4 w = *(const float4*)(Wg + idx);
    wgt[n + 0][d] = w.x; wgt[n + 1][d] = w.y;
    wgt[n + 2][d] = w.z; wgt[n + 3][d] = w.w;
  }
  int t = tid & 63, g = tid >> 6;
  double acc[4] = {0.0, 0.0, 0.0, 0.0};
  int sr = tid >> 4;
  int sc = (tid & 15) * 4;
  for (int ch = 0; ch < 16; ++ch) {
    __syncthreads();
#pragma unroll
    for (int i = 0; i < 4; ++i) {
      int r = sr + i * 16;
      float4 xv = *(const float4*)(x + (size_t)(t0 + r) * DDIM + ch * 64 + sc);
      xt[r][sc + 0] = xv.x; xt[r][sc + 1] = xv.y;
      xt[r][sc + 2] = xv.z; xt[r][sc + 3] = xv.w;
      if (xb) {
        unsigned p0 = cvt_pk_bf16(xv.x, xv.y);
        unsigned p1 = cvt_pk_bf16(xv.z, xv.w);
        *(uint2*)(xb + (size_t)(t0 + r) * DDIM + ch * 64 + sc) = make_uint2(p0, p1);
      }
    }
    __syncthreads();
#pragma unroll
    for (int d4 = 0; d4 < 16; ++d4) {
      float4 xv = *(const float4*)(&xt[t][d4 * 4]);
#pragma unroll
      for (int j = 0; j < 4; ++j) {
        float4 wv = *(const float4*)(&wgt[4 * g + j][ch * 64 + d4 * 4]);
        acc[j] += (double)xv.x * (double)wv.x + (double)xv.y * (double)wv.y +
                  (double)xv.z * (double)wv.z + (double)xv.w * (double)wv.w;
      }
    }
  }
#pragma unroll
  for (int j = 0; j < 4; ++j) lg[t][4 * g + j] = acc[j];
  __syncthreads();
  if (tid < 64) {
    double mx = lg[tid][0]; int bi = 0;
#pragma unroll
    for (int n = 1; n < NEXP; ++n)
      if (lg[tid][n] > mx) { mx = lg[tid][n]; bi = n; }
    double s = 0.0;
#pragma unroll
    for (int n = 0; n < NEXP; ++n) s += exp(lg[tid][n] - mx);
    e[t0 + tid] = bi;
    v[t0 + tid] = (float)(1.0 / s);
    atomicAdd(&hcnt[bi], 1);
  }
  __syncthreads();
  if (tid < NEXP && hcnt[tid] > 0) atomicAdd(&counts[tid], hcnt[tid]);
}

// ======================= FAST PATH (bf16 pre-converted) =====================
// R12 structure (best, 406us): 128x128 tile, BK=64, double-buffered, counted
// vmcnt, reg-prefetch within iter: { vmcnt(8); BAR; ds_read all frags;
// lgkmcnt(0); BAR; stage(t+2); setprio(1); 32 MFMA; setprio(0) }.
// Single frag set (VGPR 92, 5 waves/SIMD). 3-bit XOR granule swizzle +
// XCD expert-major block swizzle. Regressions to avoid: 256^2 tile (R8),
// 2-set frag pipeline (R10), BK=32 3-buffer ring (R13).

__global__ __launch_bounds__(256) void ffn1_fast(
    const unsigned short* __restrict__ xb, const unsigned short* __restrict__ w1t,
    const float* __restrict__ b1, const int* __restrict__ m_sel,
    const int* __restrict__ lists, unsigned short* __restrict__ H) {
  __shared__ __align__(16) unsigned short As[2][128 * 64];
  __shared__ __align__(16) unsigned short Bs[2][128 * 64];
  const int NWG = NEXP * 10 * 16;  // 2560
  const int NT = DDIM / 64;        // 16
  int bid = blockIdx.x;
  int lid = (bid & 7) * (NWG / 8) + (bid >> 3);
  int n = lid / 160;
  int rem = lid - n * 160;
  int mt = rem >> 4, ht = rem & 15;
  int M = m_sel[n];
  if (mt * 128 >= M) return;
  int tid = threadIdx.x;
  int lane = tid & 63, wid = tid >> 6;
  int wr = (wid >> 1) * 64, wc = (wid & 1) * 64;
  int rbase = tid >> 3;
  int c16 = tid & 7;
  const char* xbase = (const char*)xb;
  const char* bbase = (const char*)w1t + (((size_t)n * HDIM + (size_t)ht * 128) * DDIM) * 2;
  unsigned asrc[4], bsrc[4], ldsoff[4];
#pragma unroll
  for (int j = 0; j < 4; ++j) {
    int row = j * 32 + rbase;
    int sc = (c16 ^ (row & 7)) * 16;
    int s = mt * 128 + row;
    int tok = lists[n * CAP + (s < M ? s : 0)];
    asrc[j] = (unsigned)tok * 2048u + sc;
    bsrc[j] = (unsigned)row * 2048u + sc;
    ldsoff[j] = j * 4096 + wid * 1024;
  }
  unsigned aoff[2][4], boff[2][4];
#pragma unroll
  for (int kk = 0; kk < 2; ++kk) {
#pragma unroll
    for (int mi = 0; mi < 4; ++mi) {
      int row = wr + mi * 16 + (lane & 15);
      aoff[kk][mi] = row * 128 + (((kk * 4 + (lane >> 4)) ^ (row & 7)) * 16);
    }
#pragma unroll
    for (int ni = 0; ni < 4; ++ni) {
      int row = wc + ni * 16 + (lane & 15);
      boff[kk][ni] = row * 128 + (((kk * 4 + (lane >> 4)) ^ (row & 7)) * 16);
    }
  }
  f32x4 acc[4][4] = {};
#define STAGE1(buf, kt)                                                     \
  {                                                                         \
    unsigned ko = (unsigned)(kt) * 128u;                                    \
    _Pragma("unroll") for (int j = 0; j < 4; ++j) {                         \
      GLD16(xbase + (size_t)(asrc[j] + ko), (char*)As[buf] + ldsoff[j]);    \
      GLD16(bbase + (size_t)(bsrc[j] + ko), (char*)Bs[buf] + ldsoff[j]);    \
    }                                                                       \
  }
  STAGE1(0, 0);
  STAGE1(1, 1);
  int cur = 0;
  for (int kt = 0; kt < NT; ++kt) {
    if (kt < NT - 1) asm volatile("s_waitcnt vmcnt(8)" ::: "memory");
    else             asm volatile("s_waitcnt vmcnt(0)" ::: "memory");
    RAW_BARRIER();
    bf16x8 af[2][4], bfv[2][4];
#pragma unroll
    for (int kk = 0; kk < 2; ++kk) {
#pragma unroll
      for (int mi = 0; mi < 4; ++mi)
        af[kk][mi] = *(const bf16x8*)((const char*)As[cur] + aoff[kk][mi]);
#pragma unroll
      for (int ni = 0; ni < 4; ++ni)
        bfv[kk][ni] = *(const bf16x8*)((const char*)Bs[cur] + boff[kk][ni]);
    }
    asm volatile("s_waitcnt lgkmcnt(0)" ::: "memory");
    RAW_BARRIER();
    if (kt + 2 < NT) STAGE1(cur, kt + 2);
    __builtin_amdgcn_s_setprio(1);
#pragma unroll
    for (int kk = 0; kk < 2; ++kk)
#pragma unroll
      for (int mi = 0; mi < 4; ++mi)
#pragma unroll
        for (int ni = 0; ni < 4; ++ni)
          acc[mi][ni] = __builtin_amdgcn_mfma_f32_16x16x32_bf16(af[kk][mi], bfv[kk][ni], acc[mi][ni], 0, 0, 0);
    __builtin_amdgcn_s_setprio(0);
    cur ^= 1;
  }
  int rq = (lane >> 4) * 4;
#pragma unroll
  for (int ni = 0; ni < 4; ++ni) {
    int h = ht * 128 + wc + ni * 16 + (lane & 15);
    float bias = b1[n * HDIM + h];
#pragma unroll
    for (int mi = 0; mi < 4; ++mi) {
#pragma unroll
      for (int q = 0; q < 4; ++q) {
        int lr = wr + mi * 16 + rq + q;
        float val = acc[mi][ni][q] + bias;
        H[((size_t)n * CAP + mt * 128 + lr) * HDIM + h] = f2bf(fast_gelu(val));
      }
    }
  }
}

__global__ __launch_bounds__(256) void ffn2_fast(
    const unsigned short* __restrict__ H, const unsigned short* __restrict__ w2t,
    const float* __restrict__ b2, const int* __restrict__ m_sel,
    const int* __restrict__ lists, float* __restrict__ out) {
  __shared__ __align__(16) unsigned short As[2][128 * 64];
  __shared__ __align__(16) unsigned short Bs[2][128 * 64];
  const int NWG = NEXP * 10 * 8;  // 1280
  const int NT = HDIM / 64;       // 32
  int bid = blockIdx.x;
  int tid = threadIdx.x;
  int lid = (bid & 7) * (NWG / 8) + (bid >> 3);
  int n = lid / 80;
  int rem = lid - n * 80;
  int mt = rem >> 3, dt = rem & 7;
  int M = m_sel[n];
  if (mt * 128 >= M) return;
  int lane = tid & 63, wid = tid >> 6;
  int wr = (wid >> 1) * 64, wc = (wid & 1) * 64;
  int rbase = tid >> 3;
  int c16 = tid & 7;
  const char* abase = (const char*)H + (((size_t)n * CAP + (size_t)mt * 128) * HDIM) * 2;
  const char* bbase = (const char*)w2t + (((size_t)n * DDIM + (size_t)dt * 128) * HDIM) * 2;
  unsigned asrc[4], bsrc[4], ldsoff[4];
#pragma unroll
  for (int j = 0; j < 4; ++j) {
    int row = j * 32 + rbase;
    int sc = (c16 ^ (row & 7)) * 16;
    asrc[j] = (unsigned)row * 4096u + sc;
    bsrc[j] = (unsigned)row * 4096u + sc;
    ldsoff[j] = j * 4096 + wid * 1024;
  }
  unsigned aoff[2][4], boff[2][4];
#pragma unroll
  for (int kk = 0; kk < 2; ++kk) {
#pragma unroll
    for (int mi = 0; mi < 4; ++mi) {
      int row = wr + mi * 16 + (lane & 15);
      aoff[kk][mi] = row * 128 + (((kk * 4 + (lane >> 4)) ^ (row & 7)) * 16);
    }
#pragma unroll
    for (int ni = 0; ni < 4; ++ni) {
      int row = wc + ni * 16 + (lane & 15);
      boff[kk][ni] = row * 128 + (((kk * 4 + (lane >> 4)) ^ (row & 7)) * 16);
    }
  }
  f32x4 acc[4][4] = {};
#define STAGE2(buf, kt)                                                     \
  {                                                                         \
    unsigned ko = (unsigned)(kt) * 128u;                                    \
    _Pragma("unroll") for (int j = 0; j < 4; ++j) {                         \
      GLD16(abase + (size_t)(asrc[j] + ko), (char*)As[buf] + ldsoff[j]);    \
      GLD16(bbase + (size_t)(bsrc[j] + ko), (char*)Bs[buf] + ldsoff[j]);    \
    }                                                                       \
  }
  STAGE2(0, 0);
  STAGE2(1, 1);
  int cur = 0;
  for (int kt = 0; kt < NT; ++kt) {
    if (kt < NT - 1) asm volatile("s_waitcnt vmcnt(8)" ::: "memory");
    else             asm volatile("s_waitcnt vmcnt(0)" ::: "memory");
    RAW_BARRIER();
    bf16x8 af[2][4], bfv[2][4];
#pragma unroll
    for (int kk = 0; kk < 2; ++kk) {
#pragma unroll
      for (int mi = 0; mi < 4; ++mi)
        af[kk][mi] = *(const bf16x8*)((const char*)As[cur] + aoff[kk][mi]);
#pragma unroll
      for (int ni = 0; ni < 4; ++ni)
        bfv[kk][ni] = *(const bf16x8*)((const char*)Bs[cur] + boff[kk][ni]);
    }
    asm volatile("s_waitcnt lgkmcnt(0)" ::: "memory");
    RAW_BARRIER();
    if (kt + 2 < NT) STAGE2(cur, kt + 2);
    __builtin_amdgcn_s_setprio(1);
#pragma unroll
    for (int kk = 0; kk < 2; ++kk)
#pragma unroll
      for (int mi = 0; mi < 4; ++mi)
#pragma unroll
        for (int ni = 0; ni < 4; ++ni)
          acc[mi][ni] = __builtin_amdgcn_mfma_f32_16x16x32_bf16(af[kk][mi], bfv[kk][ni], acc[mi][ni], 0, 0, 0);
    __builtin_amdgcn_s_setprio(0);
    cur ^= 1;
  }
  int rq = (lane >> 4) * 4;
  float bias[4];
#pragma unroll
  for (int ni = 0; ni < 4; ++ni)
    bias[ni] = b2[n * DDIM + dt * 128 + wc + ni * 16 + (lane & 15)];
#pragma unroll
  for (int mi = 0; mi < 4; ++mi) {
#pragma unroll
    for (int q = 0; q < 4; ++q) {
      int lr = wr + mi * 16 + rq + q;
      int s = mt * 128 + lr;
      if (s < M) {
        int tok = lists[n * CAP + s];
#pragma unroll
        for (int ni = 0; ni < 4; ++ni) {
          int dcol = dt * 128 + wc + ni * 16 + (lane & 15);
          out[(size_t)tok * DDIM + dcol] = acc[mi][ni][q] + bias[ni];
        }
      }
    }
  }
}

// ======================= SLOW PATH (ws fallback) ============================
__global__ __launch_bounds__(256) void ffn1_slow(
    const float* __restrict__ x, const float* __restrict__ W1, const float* __restrict__ b1,
    const int* __restrict__ m_sel, const int* __restrict__ lists,
    unsigned short* __restrict__ H) {
  __shared__ unsigned short Al[128 * APITCH];
  __shared__ unsigned short Bl[128 * APITCH];
  __shared__ int rows[128];
  int n = blockIdx.z, mt = blockIdx.y, ht = blockIdx.x;
  int M = m_sel[n];
  if (mt * 128 >= M) return;
  int tid = threadIdx.x;
  if (tid < 128) {
    int s = mt * 128 + tid;
    rows[tid] = lists[n * CAP + (s < M ? s : 0)];
  }
  __syncthreads();
  f32x4 acc[4][4] = {};
  int lane = tid & 63;
  int wid = tid >> 6;
  int wr = (wid >> 1) * 64, wc = (wid & 1) * 64;
  int ar = tid >> 4, ac = (tid & 15) * 4;
  int bh = tid & 127, bk8 = (tid >> 7) * 8;
  const size_t w1base = (size_t)n * DDIM * HDIM + (size_t)ht * 128;
  for (int kt = 0; kt < DDIM / 64; ++kt) {
#pragma unroll
    for (int i = 0; i < 8; ++i) {
      int r = ar + i * 16;
      float4 xv = *(const float4*)(x + (size_t)rows[r] * DDIM + kt * 64 + ac);
      unsigned plo = (unsigned)f2bf(xv.x) | ((unsigned)f2bf(xv.y) << 16);
      unsigned phi = (unsigned)f2bf(xv.z) | ((unsigned)f2bf(xv.w) << 16);
      *(uint2*)(&Al[r * APITCH + ac]) = make_uint2(plo, phi);
    }
#pragma unroll
    for (int i = 0; i < 4; ++i) {
      int k0 = bk8 + i * 16;
      const float* wp = W1 + w1base + (size_t)(kt * 64 + k0) * HDIM + bh;
      uint4 pk;
      pk.x = (unsigned)f2bf(wp[0]) | ((unsigned)f2bf(wp[HDIM]) << 16);
      pk.y = (unsigned)f2bf(wp[2 * HDIM]) | ((unsigned)f2bf(wp[3 * HDIM]) << 16);
      pk.z = (unsigned)f2bf(wp[4 * HDIM]) | ((unsigned)f2bf(wp[5 * HDIM]) << 16);
      pk.w = (unsigned)f2bf(wp[6 * HDIM]) | ((unsigned)f2bf(wp[7 * HDIM]) << 16);
      *(uint4*)(&Bl[bh * APITCH + k0]) = pk;
    }
    __syncthreads();
#pragma unroll
    for (int kk = 0; kk < 2; ++kk) {
      bf16x8 af[4], bfr[4];
#pragma unroll
      for (int mi = 0; mi < 4; ++mi)
        af[mi] = *(const bf16x8*)(&Al[(wr + mi * 16 + (lane & 15)) * APITCH + kk * 32 + (lane >> 4) * 8]);
#pragma unroll
      for (int ni = 0; ni < 4; ++ni)
        bfr[ni] = *(const bf16x8*)(&Bl[(wc + ni * 16 + (lane & 15)) * APITCH + kk * 32 + (lane >> 4) * 8]);
#pragma unroll
      for (int mi = 0; mi < 4; ++mi)
#pragma unroll
        for (int ni = 0; ni < 4; ++ni)
          acc[mi][ni] = __builtin_amdgcn_mfma_f32_16x16x32_bf16(af[mi], bfr[ni], acc[mi][ni], 0, 0, 0);
    }
    __syncthreads();
  }
  int rq = (lane >> 4) * 4;
#pragma unroll
  for (int ni = 0; ni < 4; ++ni) {
    int h = ht * 128 + wc + ni * 16 + (lane & 15);
    float bias = b1[n * HDIM + h];
#pragma unroll
    for (int mi = 0; mi < 4; ++mi) {
#pragma unroll
      for (int q = 0; q < 4; ++q) {
        int lr = wr + mi * 16 + rq + q;
        float val = acc[mi][ni][q] + bias;
        H[((size_t)n * CAP + mt * 128 + lr) * HDIM + h] = f2bf(fast_gelu(val));
      }
    }
  }
}

__global__ __launch_bounds__(256) void ffn2_slow(
    const unsigned short* __restrict__ H, const float* __restrict__ W2, const float* __restrict__ b2,
    const int* __restrict__ m_sel, const int* __restrict__ lists,
    float* __restrict__ out) {
  __shared__ unsigned short Al[128 * APITCH];
  __shared__ unsigned short Bl[128 * APITCH];
  __shared__ int rows[128];
  int n = blockIdx.z, mt = blockIdx.y, dt = blockIdx.x;
  int M = m_sel[n];
  if (mt * 128 >= M) return;
  int tid = threadIdx.x;
  if (tid < 128) {
    int s = mt * 128 + tid;
    rows[tid] = lists[n * CAP + (s < M ? s : 0)];
  }
  __syncthreads();
  f32x4 acc[4][4] = {};
  int lane = tid & 63;
  int wid = tid >> 6;
  int wr = (wid >> 1) * 64, wc = (wid & 1) * 64;
  int ar2 = tid >> 1, ak8 = (tid & 1) * 8;
  int bh = tid & 127, bk8 = (tid >> 7) * 8;
  const size_t hbase = ((size_t)n * CAP + (size_t)mt * 128) * HDIM;
  const size_t w2base = (size_t)n * HDIM * DDIM + (size_t)dt * 128;
  for (int kt = 0; kt < HDIM / 64; ++kt) {
#pragma unroll
    for (int i = 0; i < 4; ++i) {
      int k0 = ak8 + i * 16;
      uint4 hv = *(const uint4*)(H + hbase + (size_t)ar2 * HDIM + kt * 64 + k0);
      *(uint4*)(&Al[ar2 * APITCH + k0]) = hv;
    }
#pragma unroll
    for (int i = 0; i < 4; ++i) {
      int k0 = bk8 + i * 16;
      const float* wp = W2 + w2base + (size_t)(kt * 64 + k0) * DDIM + bh;
      uint4 pk;
      pk.x = (unsigned)f2bf(wp[0]) | ((unsigned)f2bf(wp[DDIM]) << 16);
      pk.y = (unsigned)f2bf(wp[2 * DDIM]) | ((unsigned)f2bf(wp[3 * DDIM]) << 16);
      pk.z = (unsigned)f2bf(wp[4 * DDIM]) | ((unsigned)f2bf(wp[5 * DDIM]) << 16);
      pk.w = (unsigned)f2bf(wp[6 * DDIM]) | ((unsigned)f2bf(wp[7 * DDIM]) << 16);
      *(uint4*)(&Bl[bh * APITCH + k0]) = pk;
    }
    __syncthreads();
#pragma unroll
    for (int kk = 0; kk < 2; ++kk) {
      bf16x8 af[4], bfr[4];
#pragma unroll
      for (int mi = 0; mi < 4; ++mi)
        af[mi] = *(const bf16x8*)(&Al[(wr + mi * 16 + (lane & 15)) * APITCH + kk * 32 + (lane >> 4) * 8]);
#pragma unroll
      for (int ni = 0; ni < 4; ++ni)
        bfr[ni] = *(const bf16x8*)(&Bl[(wc + ni * 16 + (lane & 15)) * APITCH + kk * 32 + (lane >> 4) * 8]);
#pragma unroll
      for (int mi = 0; mi < 4; ++mi)
#pragma unroll
        for (int ni = 0; ni < 4; ++ni)
          acc[mi][ni] = __builtin_amdgcn_mfma_f32_16x16x32_bf16(af[mi], bfr[ni], acc[mi][ni], 0, 0, 0);
    }
    __syncthreads();
  }
  int rq = (lane >> 4) * 4;
#pragma unroll
  for (int mi = 0; mi < 4; ++mi) {
#pragma unroll
    for (int q = 0; q < 4; ++q) {
      int lr = wr + mi * 16 + rq + q;
      int s = mt * 128 + lr;
      if (s < M) {
        int tok = rows[lr];
#pragma unroll
        for (int ni = 0; ni < 4; ++ni) {
          int dcol = dt * 128 + wc + ni * 16 + (lane & 15);
          out[(size_t)tok * DDIM + dcol] = acc[mi][ni][q] + b2[n * DDIM + dcol];
        }
      }
    }
  }
}

// ---------------- passthrough: one wave per row, 1024 blocks ----------------
__global__ __launch_bounds__(256) void passthrough_kernel(
    const float* __restrict__ x, const int* __restrict__ flags,
    float* __restrict__ out) {
  int lane = threadIdx.x & 63;
  int w = threadIdx.x >> 6;
  int base = blockIdx.x * 16;
  for (int r = base + w; r < base + 16; r += 4) {
    if (flags[r]) continue;
    const float4* s = (const float4*)(x + (size_t)r * DDIM);
    float4* d = (float4*)(out + (size_t)r * DDIM);
#pragma unroll
    for (int i = 0; i < 4; ++i) d[lane + i * 64] = s[lane + i * 64];
  }
}

extern "C" void kernel_launch(void* const* d_in, const int* in_sizes, int n_in,
                              void* d_out, int out_size, void* d_ws, size_t ws_size,
                              hipStream_t stream) {
  const float* x  = (const float*)d_in[0];
  const float* Wg = (const float*)d_in[1];
  const float* W1 = (const float*)d_in[2];
  const float* b1 = (const float*)d_in[3];
  const float* W2 = (const float*)d_in[4];
  const float* b2 = (const float*)d_in[5];
  float* out = (float*)d_out;
  char* ws = (char*)d_ws;
  int* counts = (int*)ws;
  int* m_sel  = (int*)(ws + 64);
  int* flags  = (int*)(ws + 128);
  int* e      = (int*)(ws + 128 + 4 * BT);
  float* v    = (float*)(ws + 128 + 8 * BT);
  int* lists  = (int*)(ws + 128 + 12 * BT);

  const size_t MB = 1024 * 1024;
  unsigned short* xb  = (unsigned short*)(ws + 1 * MB);
  unsigned short* w1t = (unsigned short*)(ws + 33 * MB);
  unsigned short* w2t = (unsigned short*)(ws + 97 * MB);
  unsigned short* Hf  = (unsigned short*)(ws + 161 * MB);
  bool fast = ws_size >= 242 * MB;

  zero_meta_kernel<<<1, 64, 0, stream>>>(counts);
  if (fast) {
    prep_kernel<<<256 + 16384, 256, 0, stream>>>(x, Wg, e, v, counts, xb, flags,
                                                 W1, W2, w1t, w2t);
    select_kernel<<<NEXP, 256, 0, stream>>>(e, v, counts, m_sel, lists, flags);
    ffn1_fast<<<NEXP * 10 * 16, 256, 0, stream>>>(xb, w1t, b1, m_sel, lists, Hf);
    ffn2_fast<<<NEXP * 10 * 8, 256, 0, stream>>>(Hf, w2t, b2, m_sel, lists, out);
  } else {
    unsigned short* Hs = (unsigned short*)(ws + 1 * MB);
    gate_kernel<<<BT / 64, 256, 0, stream>>>(x, Wg, e, v, counts, (unsigned short*)nullptr, flags);
    select_kernel<<<NEXP, 256, 0, stream>>>(e, v, counts, m_sel, lists, flags);
    ffn1_slow<<<dim3(HDIM / 128, CAP / 128, NEXP), 256, 0, stream>>>(x, W1, b1, m_sel, lists, Hs);
    ffn2_slow<<<dim3(DDIM / 128, CAP / 128, NEXP), 256, 0, stream>>>(Hs, W2, b2, m_sel, lists, out);
  }
  passthrough_kernel<<<BT / 16, 256, 0, stream>>>(x, flags, out);
}

// Round 15
// 389.599 us; speedup vs baseline: 1.0763x; 1.0142x over previous
//
#include <hip/hip_runtime.h>
#include <hip/hip_bf16.h>
#include <math.h>

#define BT 16384
#define DDIM 1024
#define NEXP 16
#define HDIM 2048
#define CAP 1280
#define APITCH 72

typedef __bf16 bf16x8 __attribute__((ext_vector_type(8)));
typedef float f32x4 __attribute__((ext_vector_type(4)));

__device__ __forceinline__ unsigned short f2bf(float f) {
  unsigned u = __float_as_uint(f);
  u += 0x7FFFu + ((u >> 16) & 1u);
  return (unsigned short)(u >> 16);
}

// HW packed fp32->bf16 (RNE, identical to f2bf): dst.lo=cvt(a), dst.hi=cvt(b)
__device__ __forceinline__ unsigned cvt_pk_bf16(float a, float b) {
  unsigned r;
  asm("v_cvt_pk_bf16_f32 %0, %1, %2" : "=v"(r) : "v"(a), "v"(b));
  return r;
}

// gelu(tanh approx) == v * sigmoid(2z); hardware v_exp_f32 path.
__device__ __forceinline__ float fast_gelu(float v) {
  float z = 0.7978845608028654f * (v + 0.044715f * v * v * v);
  return v / (1.0f + __expf(-2.0f * z));
}

#define GLD16(g, l)                                                        \
  __builtin_amdgcn_global_load_lds(                                        \
      (const __attribute__((address_space(1))) unsigned int*)(g),          \
      (__attribute__((address_space(3))) unsigned int*)(l), 16, 0, 0)

// Raw barrier without the vmcnt(0) drain __syncthreads would emit.
#define RAW_BARRIER()                          \
  {                                            \
    __builtin_amdgcn_sched_barrier(0);         \
    __builtin_amdgcn_s_barrier();              \
    __builtin_amdgcn_sched_barrier(0);         \
  }

__global__ void zero_meta_kernel(int* p) {
  int i = threadIdx.x;
  if (i < 32) p[i] = 0;  // counts[16] + m_sel[16]
}

// ======== fused prep: blocks [0,256) = gate (streamed Wg chunks, 30KB LDS);
// ========             blocks [256,..) = W1/W2 transpose+cvt into TILED layout.
// Weights stored as 64x64 bf16 tiles (8KB, [col][row] within tile):
//   w1t: expert n, tile (i_h, i_d) at (n*512 + i_h*16 + i_d)*8192 bytes
//   w2t: expert n, tile (i_d, i_h) at (n*512 + i_d*32 + i_h)*8192 bytes
// Transpose writes each tile as two contiguous 4KB bursts (tid*16) -> fixes
// R14's 128B-scattered HBM writes (prep was 1.9TB/s, 170us).
__global__ __launch_bounds__(256) void prep_kernel(
    const float* __restrict__ x, const float* __restrict__ Wg,
    int* __restrict__ e, float* __restrict__ v, int* __restrict__ counts,
    unsigned short* __restrict__ xb, int* __restrict__ flags,
    const float* __restrict__ W1, const float* __restrict__ W2,
    unsigned short* __restrict__ w1t, unsigned short* __restrict__ w2t) {
  __shared__ __align__(16) char smem[30016];
  int bid = blockIdx.x;
  int tid = threadIdx.x;
  if (bid < 256) {
    // ---------------- gate: 64 tokens/block ----------------
    float* xt = (float*)smem;                       // [64][68]  17408B
    double* lg = (double*)(smem + 17408);           // [64][16]   8192B
    float* wgt_c = (float*)(smem + 25600);          // [16][68]   4352B
    int* hcnt = (int*)(smem + 29952);               // [16]
    int t0 = bid * 64;
    if (tid < NEXP) hcnt[tid] = 0;
    if (tid < 64) flags[t0 + tid] = 0;
    int t = tid & 63, g = tid >> 6;
    double acc[4] = {0.0, 0.0, 0.0, 0.0};
    int sr = tid >> 4;
    int sc = (tid & 15) * 4;
    int wd = tid >> 2, wn = (tid & 3) * 4;
    for (int ch = 0; ch < 16; ++ch) {
      __syncthreads();
#pragma unroll
      for (int i = 0; i < 4; ++i) {
        int r = sr + i * 16;
        float4 xv = *(const float4*)(x + (size_t)(t0 + r) * DDIM + ch * 64 + sc);
        xt[r * 68 + sc + 0] = xv.x; xt[r * 68 + sc + 1] = xv.y;
        xt[r * 68 + sc + 2] = xv.z; xt[r * 68 + sc + 3] = xv.w;
        unsigned p0 = cvt_pk_bf16(xv.x, xv.y);
        unsigned p1 = cvt_pk_bf16(xv.z, xv.w);
        *(uint2*)(xb + (size_t)(t0 + r) * DDIM + ch * 64 + sc) = make_uint2(p0, p1);
      }
      {
        float4 w = *(const float4*)(Wg + ch * 1024 + tid * 4);
        wgt_c[(wn + 0) * 68 + wd] = w.x;
        wgt_c[(wn + 1) * 68 + wd] = w.y;
        wgt_c[(wn + 2) * 68 + wd] = w.z;
        wgt_c[(wn + 3) * 68 + wd] = w.w;
      }
      __syncthreads();
#pragma unroll
      for (int d4 = 0; d4 < 16; ++d4) {
        float4 xv = *(const float4*)(&xt[t * 68 + d4 * 4]);
#pragma unroll
        for (int j = 0; j < 4; ++j) {
          float4 wv = *(const float4*)(&wgt_c[(4 * g + j) * 68 + d4 * 4]);
          acc[j] += (double)xv.x * (double)wv.x + (double)xv.y * (double)wv.y +
                    (double)xv.z * (double)wv.z + (double)xv.w * (double)wv.w;
        }
      }
    }
#pragma unroll
    for (int j = 0; j < 4; ++j) lg[t * 16 + 4 * g + j] = acc[j];
    __syncthreads();
    if (tid < 64) {
      double mx = lg[tid * 16]; int bi = 0;
#pragma unroll
      for (int n = 1; n < NEXP; ++n)
        if (lg[tid * 16 + n] > mx) { mx = lg[tid * 16 + n]; bi = n; }
      double s = 0.0;
#pragma unroll
      for (int n = 0; n < NEXP; ++n) s += exp(lg[tid * 16 + n] - mx);
      e[t0 + tid] = bi;
      v[t0 + tid] = (float)(1.0 / s);
      atomicAdd(&hcnt[bi], 1);
    }
    __syncthreads();
    if (tid < NEXP && hcnt[tid] > 0) atomicAdd(&counts[tid], hcnt[tid]);
    return;
  }
  // ---------------- transpose + fp32->bf16 into tiled layout ----------------
  float* tile = (float*)smem;  // [64][65]
  int b = bid - 256;
  const float* in;
  unsigned short* outp;
  int C, n, bx, by;
  size_t tile_off;
  if (b < 8192) {  // W1 [n][1024][2048]: bx = i_h (0..31), by = i_d (0..15)
    in = W1; outp = w1t; C = HDIM;
    n = b >> 9; int rem = b & 511; by = rem >> 5; bx = rem & 31;
    tile_off = ((size_t)n * 512 + (size_t)bx * 16 + by) * 8192;
  } else {         // W2 [n][2048][1024]: bx = i_d (0..15), by = i_h (0..31)
    b -= 8192;
    in = W2; outp = w2t; C = DDIM;
    n = b >> 9; int rem = b & 511; by = rem >> 4; bx = rem & 15;
    tile_off = ((size_t)n * 512 + (size_t)bx * 32 + by) * 8192;
  }
  const float* src = in + (size_t)n * DDIM * HDIM;
  int r0 = by * 64, c0 = bx * 64;
  int lr = tid >> 2, lq = tid & 3;
#pragma unroll
  for (int i = 0; i < 4; ++i) {
    float4 vv = *(const float4*)(src + (size_t)(r0 + lr) * C + c0 + i * 16 + lq * 4);
    *(float4*)(&tile[lr * 65 + i * 16 + lq * 4]) = vv;
  }
  __syncthreads();
  char* dstT = (char*)outp + tile_off;
  int oc2 = tid >> 3, lq2 = tid & 7;
#pragma unroll
  for (int p = 0; p < 2; ++p) {
    int oc = p * 32 + oc2;
    int rb = lq2 * 8;
    uint4 pk;
    pk.x = cvt_pk_bf16(tile[(rb + 0) * 65 + oc], tile[(rb + 1) * 65 + oc]);
    pk.y = cvt_pk_bf16(tile[(rb + 2) * 65 + oc], tile[(rb + 3) * 65 + oc]);
    pk.z = cvt_pk_bf16(tile[(rb + 4) * 65 + oc], tile[(rb + 5) * 65 + oc]);
    pk.w = cvt_pk_bf16(tile[(rb + 6) * 65 + oc], tile[(rb + 7) * 65 + oc]);
    // tile element (col=oc, row=rb..rb+7) -> byte oc*128 + rb*2 == p*4096 + tid*16
    *(uint4*)(dstT + p * 4096 + tid * 16) = pk;
  }
}

// ---------------- select: per-expert token set under capacity ---------------
__global__ void select_kernel(const int* __restrict__ e, const float* __restrict__ v,
                              const int* __restrict__ counts, int* __restrict__ m_sel,
                              int* __restrict__ lists, int* __restrict__ flags) {
  int n = blockIdx.x;
  int tid = threadIdx.x;
  int cnt = counts[n];
  __shared__ int pos;
  if (tid == 0) pos = 0;
  __syncthreads();
  if (cnt <= CAP) {
    for (int t = tid; t < BT; t += 256) {
      if (e[t] == n) {
        int p = atomicAdd(&pos, 1);
        lists[n * CAP + p] = t;
        flags[t] = 1;
      }
    }
    __syncthreads();
    if (tid == 0) m_sel[n] = pos;
  } else {
    __shared__ int scnt;
    unsigned lo = 0u, hi = 0x7F800000u;
    while (hi - lo > 1u) {
      unsigned mid = lo + ((hi - lo) >> 1);
      if (tid == 0) scnt = 0;
      __syncthreads();
      int c = 0;
      for (int t = tid; t < BT; t += 256)
        if (e[t] == n && __float_as_uint(v[t]) >= mid) c++;
      atomicAdd(&scnt, c);
      __syncthreads();
      int tot = scnt;
      __syncthreads();
      if (tot >= CAP) lo = mid; else hi = mid;
    }
    for (int t = tid; t < BT; t += 256) {
      if (e[t] == n && __float_as_uint(v[t]) > lo) {
        int p = atomicAdd(&pos, 1);
        lists[n * CAP + p] = t;
        flags[t] = 1;
      }
    }
    __syncthreads();
    if (tid == 0) {
      int p = pos;
      for (int t = 0; t < BT && p < CAP; ++t) {
        if (e[t] == n && __float_as_uint(v[t]) == lo) {
          lists[n * CAP + p] = t; flags[t] = 1; ++p;
        }
      }
      m_sel[n] = p;
    }
  }
}

// ---------------- gate (slow path only, resident Wg table) ------------------
__global__ __launch_bounds__(256) void gate_kernel(
    const float* __restrict__ x, const float* __restrict__ Wg,
    int* __restrict__ e, float* __restrict__ v, int* __restrict__ counts,
    unsigned short* __restrict__ xb, int* __restrict__ flags) {
  __shared__ float wgt[NEXP][DDIM];
  __shared__ float xt[64][68];
  __shared__ double lg[64][NEXP];
  __shared__ int hcnt[NEXP];
  int tid = threadIdx.x;
  int t0 = blockIdx.x * 64;
  if (tid < NEXP) hcnt[tid] = 0;
  if (tid < 64) flags[t0 + tid] = 0;
  for (int i = tid; i < DDIM * NEXP / 4; i += 256) {
    int idx = i * 4;
    int d = idx >> 4, n = idx & 15;
    float4 w = *(const float4*)(Wg + idx);
    wgt[n + 0][d] = w.x; wgt[n + 1][d] = w.y;
    wgt[n + 2][d] = w.z; wgt[n + 3][d] = w.w;
  }
  int t = tid & 63, g = tid >> 6;
  double acc[4] = {0.0, 0.0, 0.0, 0.0};
  int sr = tid >> 4;
  int sc = (tid & 15) * 4;
  for (int ch = 0; ch < 16; ++ch) {
    __syncthreads();
#pragma unroll
    for (int i = 0; i < 4; ++i) {
      int r = sr + i * 16;
      float4 xv = *(const float4*)(x + (size_t)(t0 + r) * DDIM + ch * 64 + sc);
      xt[r][sc + 0] = xv.x; xt[r][sc + 1] = xv.y;
      xt[r][sc + 2] = xv.z; xt[r][sc + 3] = xv.w;
      if (xb) {
        unsigned p0 = cvt_pk_bf16(xv.x, xv.y);
        unsigned p1 = cvt_pk_bf16(xv.z, xv.w);
        *(uint2*)(xb + (size_t)(t0 + r) * DDIM + ch * 64 + sc) = make_uint2(p0, p1);
      }
    }
    __syncthreads();
#pragma unroll
    for (int d4 = 0; d4 < 16; ++d4) {
      float4 xv = *(const float4*)(&xt[t][d4 * 4]);
#pragma unroll
      for (int j = 0; j < 4; ++j) {
        float4 wv = *(const float4*)(&wgt[4 * g + j][ch * 64 + d4 * 4]);
        acc[j] += (double)xv.x * (double)wv.x + (double)xv.y * (double)wv.y +
                  (double)xv.z * (double)wv.z + (double)xv.w * (double)wv.w;
      }
    }
  }
#pragma unroll
  for (int j = 0; j < 4; ++j) lg[t][4 * g + j] = acc[j];
  __syncthreads();
  if (tid < 64) {
    double mx = lg[tid][0]; int bi = 0;
#pragma unroll
    for (int n = 1; n < NEXP; ++n)
      if (lg[tid][n] > mx) { mx = lg[tid][n]; bi = n; }
    double s = 0.0;
#pragma unroll
    for (int n = 0; n < NEXP; ++n) s += exp(lg[tid][n] - mx);
    e[t0 + tid] = bi;
    v[t0 + tid] = (float)(1.0 / s);
    atomicAdd(&hcnt[bi], 1);
  }
  __syncthreads();
  if (tid < NEXP && hcnt[tid] > 0) atomicAdd(&counts[tid], hcnt[tid]);
}

// ======================= FAST PATH (bf16 pre-converted) =====================
// R12 FFN structure (best): 128x128 tile, BK=64, double-buffered, counted
// vmcnt, reg-prefetch within iter. B-panels now read from TILED weights:
// granule byte = tile_id*8192 + (row&63)*128 + g*16, kt stride = 8192.
// Regressions to avoid: 256^2 tile (R8), 2-set frags (R10), BK=32 ring (R13).

__global__ __launch_bounds__(256) void ffn1_fast(
    const unsigned short* __restrict__ xb, const unsigned short* __restrict__ w1t,
    const float* __restrict__ b1, const int* __restrict__ m_sel,
    const int* __restrict__ lists, unsigned short* __restrict__ H) {
  __shared__ __align__(16) unsigned short As[2][128 * 64];
  __shared__ __align__(16) unsigned short Bs[2][128 * 64];
  const int NWG = NEXP * 10 * 16;  // 2560
  const int NT = DDIM / 64;        // 16
  int bid = blockIdx.x;
  int lid = (bid & 7) * (NWG / 8) + (bid >> 3);
  int n = lid / 160;
  int rem = lid - n * 160;
  int mt = rem >> 4, ht = rem & 15;
  int M = m_sel[n];
  if (mt * 128 >= M) return;
  int tid = threadIdx.x;
  int lane = tid & 63, wid = tid >> 6;
  int wr = (wid >> 1) * 64, wc = (wid & 1) * 64;
  int rbase = tid >> 3;
  int c16 = tid & 7;
  const char* xbase = (const char*)xb;
  const char* bbase = (const char*)w1t + (size_t)n * (DDIM * HDIM * 2);
  unsigned asrc[4], bsrc[4], ldsoff[4];
#pragma unroll
  for (int j = 0; j < 4; ++j) {
    int row = j * 32 + rbase;
    int g = c16 ^ (row & 7);
    int s = mt * 128 + row;
    int tok = lists[n * CAP + (s < M ? s : 0)];
    asrc[j] = (unsigned)tok * 2048u + g * 16;
    bsrc[j] = (unsigned)((ht * 2 + (row >> 6)) * 16) * 8192u +
              (unsigned)(row & 63) * 128u + g * 16;
    ldsoff[j] = j * 4096 + wid * 1024;
  }
  unsigned aoff[2][4], boff[2][4];
#pragma unroll
  for (int kk = 0; kk < 2; ++kk) {
#pragma unroll
    for (int mi = 0; mi < 4; ++mi) {
      int row = wr + mi * 16 + (lane & 15);
      aoff[kk][mi] = row * 128 + (((kk * 4 + (lane >> 4)) ^ (row & 7)) * 16);
    }
#pragma unroll
    for (int ni = 0; ni < 4; ++ni) {
      int row = wc + ni * 16 + (lane & 15);
      boff[kk][ni] = row * 128 + (((kk * 4 + (lane >> 4)) ^ (row & 7)) * 16);
    }
  }
  f32x4 acc[4][4] = {};
#define STAGE1(buf, kt)                                                     \
  {                                                                         \
    unsigned koa = (unsigned)(kt) * 128u;                                   \
    unsigned kob = (unsigned)(kt) * 8192u;                                  \
    _Pragma("unroll") for (int j = 0; j < 4; ++j) {                         \
      GLD16(xbase + (size_t)(asrc[j] + koa), (char*)As[buf] + ldsoff[j]);   \
      GLD16(bbase + (size_t)(bsrc[j] + kob), (char*)Bs[buf] + ldsoff[j]);   \
    }                                                                       \
  }
  STAGE1(0, 0);
  STAGE1(1, 1);
  int cur = 0;
  for (int kt = 0; kt < NT; ++kt) {
    if (kt < NT - 1) asm volatile("s_waitcnt vmcnt(8)" ::: "memory");
    else             asm volatile("s_waitcnt vmcnt(0)" ::: "memory");
    RAW_BARRIER();
    bf16x8 af[2][4], bfv[2][4];
#pragma unroll
    for (int kk = 0; kk < 2; ++kk) {
#pragma unroll
      for (int mi = 0; mi < 4; ++mi)
        af[kk][mi] = *(const bf16x8*)((const char*)As[cur] + aoff[kk][mi]);
#pragma unroll
      for (int ni = 0; ni < 4; ++ni)
        bfv[kk][ni] = *(const bf16x8*)((const char*)Bs[cur] + boff[kk][ni]);
    }
    asm volatile("s_waitcnt lgkmcnt(0)" ::: "memory");
    RAW_BARRIER();
    if (kt + 2 < NT) STAGE1(cur, kt + 2);
    __builtin_amdgcn_s_setprio(1);
#pragma unroll
    for (int kk = 0; kk < 2; ++kk)
#pragma unroll
      for (int mi = 0; mi < 4; ++mi)
#pragma unroll
        for (int ni = 0; ni < 4; ++ni)
          acc[mi][ni] = __builtin_amdgcn_mfma_f32_16x16x32_bf16(af[kk][mi], bfv[kk][ni], acc[mi][ni], 0, 0, 0);
    __builtin_amdgcn_s_setprio(0);
    cur ^= 1;
  }
  int rq = (lane >> 4) * 4;
#pragma unroll
  for (int ni = 0; ni < 4; ++ni) {
    int h = ht * 128 + wc + ni * 16 + (lane & 15);
    float bias = b1[n * HDIM + h];
#pragma unroll
    for (int mi = 0; mi < 4; ++mi) {
#pragma unroll
      for (int q = 0; q < 4; ++q) {
        int lr = wr + mi * 16 + rq + q;
        float val = acc[mi][ni][q] + bias;
        H[((size_t)n * CAP + mt * 128 + lr) * HDIM + h] = f2bf(fast_gelu(val));
      }
    }
  }
}

__global__ __launch_bounds__(256) void ffn2_fast(
    const unsigned short* __restrict__ H, const unsigned short* __restrict__ w2t,
    const float* __restrict__ b2, const int* __restrict__ m_sel,
    const int* __restrict__ lists, float* __restrict__ out) {
  __shared__ __align__(16) unsigned short As[2][128 * 64];
  __shared__ __align__(16) unsigned short Bs[2][128 * 64];
  const int NWG = NEXP * 10 * 8;  // 1280
  const int NT = HDIM / 64;       // 32
  int bid = blockIdx.x;
  int tid = threadIdx.x;
  int lid = (bid & 7) * (NWG / 8) + (bid >> 3);
  int n = lid / 80;
  int rem = lid - n * 80;
  int mt = rem >> 3, dt = rem & 7;
  int M = m_sel[n];
  if (mt * 128 >= M) return;
  int lane = tid & 63, wid = tid >> 6;
  int wr = (wid >> 1) * 64, wc = (wid & 1) * 64;
  int rbase = tid >> 3;
  int c16 = tid & 7;
  const char* abase = (const char*)H + (((size_t)n * CAP + (size_t)mt * 128) * HDIM) * 2;
  const char* bbase = (const char*)w2t + (size_t)n * (DDIM * HDIM * 2);
  unsigned asrc[4], bsrc[4], ldsoff[4];
#pragma unroll
  for (int j = 0; j < 4; ++j) {
    int row = j * 32 + rbase;
    int g = c16 ^ (row & 7);
    asrc[j] = (unsigned)row * 4096u + g * 16;
    bsrc[j] = (unsigned)((dt * 2 + (row >> 6)) * 32) * 8192u +
              (unsigned)(row & 63) * 128u + g * 16;
    ldsoff[j] = j * 4096 + wid * 1024;
  }
  unsigned aoff[2][4], boff[2][4];
#pragma unroll
  for (int kk = 0; kk < 2; ++kk) {
#pragma unroll
    for (int mi = 0; mi < 4; ++mi) {
      int row = wr + mi * 16 + (lane & 15);
      aoff[kk][mi] = row * 128 + (((kk * 4 + (lane >> 4)) ^ (row & 7)) * 16);
    }
#pragma unroll
    for (int ni = 0; ni < 4; ++ni) {
      int row = wc + ni * 16 + (lane & 15);
      boff[kk][ni] = row * 128 + (((kk * 4 + (lane >> 4)) ^ (row & 7)) * 16);
    }
  }
  f32x4 acc[4][4] = {};
#define STAGE2(buf, kt)                                                     \
  {                                                                         \
    unsigned koa = (unsigned)(kt) * 128u;                                   \
    unsigned kob = (unsigned)(kt) * 8192u;                                  \
    _Pragma("unroll") for (int j = 0; j < 4; ++j) {                         \
      GLD16(abase + (size_t)(asrc[j] + koa), (char*)As[buf] + ldsoff[j]);   \
      GLD16(bbase + (size_t)(bsrc[j] + kob), (char*)Bs[buf] + ldsoff[j]);   \
    }                                                                       \
  }
  STAGE2(0, 0);
  STAGE2(1, 1);
  int cur = 0;
  for (int kt = 0; kt < NT; ++kt) {
    if (kt < NT - 1) asm volatile("s_waitcnt vmcnt(8)" ::: "memory");
    else             asm volatile("s_waitcnt vmcnt(0)" ::: "memory");
    RAW_BARRIER();
    bf16x8 af[2][4], bfv[2][4];
#pragma unroll
    for (int kk = 0; kk < 2; ++kk) {
#pragma unroll
      for (int mi = 0; mi < 4; ++mi)
        af[kk][mi] = *(const bf16x8*)((const char*)As[cur] + aoff[kk][mi]);
#pragma unroll
      for (int ni = 0; ni < 4; ++ni)
        bfv[kk][ni] = *(const bf16x8*)((const char*)Bs[cur] + boff[kk][ni]);
    }
    asm volatile("s_waitcnt lgkmcnt(0)" ::: "memory");
    RAW_BARRIER();
    if (kt + 2 < NT) STAGE2(cur, kt + 2);
    __builtin_amdgcn_s_setprio(1);
#pragma unroll
    for (int kk = 0; kk < 2; ++kk)
#pragma unroll
      for (int mi = 0; mi < 4; ++mi)
#pragma unroll
        for (int ni = 0; ni < 4; ++ni)
          acc[mi][ni] = __builtin_amdgcn_mfma_f32_16x16x32_bf16(af[kk][mi], bfv[kk][ni], acc[mi][ni], 0, 0, 0);
    __builtin_amdgcn_s_setprio(0);
    cur ^= 1;
  }
  int rq = (lane >> 4) * 4;
  float bias[4];
#pragma unroll
  for (int ni = 0; ni < 4; ++ni)
    bias[ni] = b2[n * DDIM + dt * 128 + wc + ni * 16 + (lane & 15)];
#pragma unroll
  for (int mi = 0; mi < 4; ++mi) {
#pragma unroll
    for (int q = 0; q < 4; ++q) {
      int lr = wr + mi * 16 + rq + q;
      int s = mt * 128 + lr;
      if (s < M) {
        int tok = lists[n * CAP + s];
#pragma unroll
        for (int ni = 0; ni < 4; ++ni) {
          int dcol = dt * 128 + wc + ni * 16 + (lane & 15);
          out[(size_t)tok * DDIM + dcol] = acc[mi][ni][q] + bias[ni];
        }
      }
    }
  }
}

// ======================= SLOW PATH (ws fallback) ============================
__global__ __launch_bounds__(256) void ffn1_slow(
    const float* __restrict__ x, const float* __restrict__ W1, const float* __restrict__ b1,
    const int* __restrict__ m_sel, const int* __restrict__ lists,
    unsigned short* __restrict__ H) {
  __shared__ unsigned short Al[128 * APITCH];
  __shared__ unsigned short Bl[128 * APITCH];
  __shared__ int rows[128];
  int n = blockIdx.z, mt = blockIdx.y, ht = blockIdx.x;
  int M = m_sel[n];
  if (mt * 128 >= M) return;
  int tid = threadIdx.x;
  if (tid < 128) {
    int s = mt * 128 + tid;
    rows[tid] = lists[n * CAP + (s < M ? s : 0)];
  }
  __syncthreads();
  f32x4 acc[4][4] = {};
  int lane = tid & 63;
  int wid = tid >> 6;
  int wr = (wid >> 1) * 64, wc = (wid & 1) * 64;
  int ar = tid >> 4, ac = (tid & 15) * 4;
  int bh = tid & 127, bk8 = (tid >> 7) * 8;
  const size_t w1base = (size_t)n * DDIM * HDIM + (size_t)ht * 128;
  for (int kt = 0; kt < DDIM / 64; ++kt) {
#pragma unroll
    for (int i = 0; i < 8; ++i) {
      int r = ar + i * 16;
      float4 xv = *(const float4*)(x + (size_t)rows[r] * DDIM + kt * 64 + ac);
      unsigned plo = (unsigned)f2bf(xv.x) | ((unsigned)f2bf(xv.y) << 16);
      unsigned phi = (unsigned)f2bf(xv.z) | ((unsigned)f2bf(xv.w) << 16);
      *(uint2*)(&Al[r * APITCH + ac]) = make_uint2(plo, phi);
    }
#pragma unroll
    for (int i = 0; i < 4; ++i) {
      int k0 = bk8 + i * 16;
      const float* wp = W1 + w1base + (size_t)(kt * 64 + k0) * HDIM + bh;
      uint4 pk;
      pk.x = (unsigned)f2bf(wp[0]) | ((unsigned)f2bf(wp[HDIM]) << 16);
      pk.y = (unsigned)f2bf(wp[2 * HDIM]) | ((unsigned)f2bf(wp[3 * HDIM]) << 16);
      pk.z = (unsigned)f2bf(wp[4 * HDIM]) | ((unsigned)f2bf(wp[5 * HDIM]) << 16);
      pk.w = (unsigned)f2bf(wp[6 * HDIM]) | ((unsigned)f2bf(wp[7 * HDIM]) << 16);
      *(uint4*)(&Bl[bh * APITCH + k0]) = pk;
    }
    __syncthreads();
#pragma unroll
    for (int kk = 0; kk < 2; ++kk) {
      bf16x8 af[4], bfr[4];
#pragma unroll
      for (int mi = 0; mi < 4; ++mi)
        af[mi] = *(const bf16x8*)(&Al[(wr + mi * 16 + (lane & 15)) * APITCH + kk * 32 + (lane >> 4) * 8]);
#pragma unroll
      for (int ni = 0; ni < 4; ++ni)
        bfr[ni] = *(const bf16x8*)(&Bl[(wc + ni * 16 + (lane & 15)) * APITCH + kk * 32 + (lane >> 4) * 8]);
#pragma unroll
      for (int mi = 0; mi < 4; ++mi)
#pragma unroll
        for (int ni = 0; ni < 4; ++ni)
          acc[mi][ni] = __builtin_amdgcn_mfma_f32_16x16x32_bf16(af[mi], bfr[ni], acc[mi][ni], 0, 0, 0);
    }
    __syncthreads();
  }
  int rq = (lane >> 4) * 4;
#pragma unroll
  for (int ni = 0; ni < 4; ++ni) {
    int h = ht * 128 + wc + ni * 16 + (lane & 15);
    float bias = b1[n * HDIM + h];
#pragma unroll
    for (int mi = 0; mi < 4; ++mi) {
#pragma unroll
      for (int q = 0; q < 4; ++q) {
        int lr = wr + mi * 16 + rq + q;
        float val = acc[mi][ni][q] + bias;
        H[((size_t)n * CAP + mt * 128 + lr) * HDIM + h] = f2bf(fast_gelu(val));
      }
    }
  }
}

__global__ __launch_bounds__(256) void ffn2_slow(
    const unsigned short* __restrict__ H, const float* __restrict__ W2, const float* __restrict__ b2,
    const int* __restrict__ m_sel, const int* __restrict__ lists,
    float* __restrict__ out) {
  __shared__ unsigned short Al[128 * APITCH];
  __shared__ unsigned short Bl[128 * APITCH];
  __shared__ int rows[128];
  int n = blockIdx.z, mt = blockIdx.y, dt = blockIdx.x;
  int M = m_sel[n];
  if (mt * 128 >= M) return;
  int tid = threadIdx.x;
  if (tid < 128) {
    int s = mt * 128 + tid;
    rows[tid] = lists[n * CAP + (s < M ? s : 0)];
  }
  __syncthreads();
  f32x4 acc[4][4] = {};
  int lane = tid & 63;
  int wid = tid >> 6;
  int wr = (wid >> 1) * 64, wc = (wid & 1) * 64;
  int ar2 = tid >> 1, ak8 = (tid & 1) * 8;
  int bh = tid & 127, bk8 = (tid >> 7) * 8;
  const size_t hbase = ((size_t)n * CAP + (size_t)mt * 128) * HDIM;
  const size_t w2base = (size_t)n * HDIM * DDIM + (size_t)dt * 128;
  for (int kt = 0; kt < HDIM / 64; ++kt) {
#pragma unroll
    for (int i = 0; i < 4; ++i) {
      int k0 = ak8 + i * 16;
      uint4 hv = *(const uint4*)(H + hbase + (size_t)ar2 * HDIM + kt * 64 + k0);
      *(uint4*)(&Al[ar2 * APITCH + k0]) = hv;
    }
#pragma unroll
    for (int i = 0; i < 4; ++i) {
      int k0 = bk8 + i * 16;
      const float* wp = W2 + w2base + (size_t)(kt * 64 + k0) * DDIM + bh;
      uint4 pk;
      pk.x = (unsigned)f2bf(wp[0]) | ((unsigned)f2bf(wp[DDIM]) << 16);
      pk.y = (unsigned)f2bf(wp[2 * DDIM]) | ((unsigned)f2bf(wp[3 * DDIM]) << 16);
      pk.z = (unsigned)f2bf(wp[4 * DDIM]) | ((unsigned)f2bf(wp[5 * DDIM]) << 16);
      pk.w = (unsigned)f2bf(wp[6 * DDIM]) | ((unsigned)f2bf(wp[7 * DDIM]) << 16);
      *(uint4*)(&Bl[bh * APITCH + k0]) = pk;
    }
    __syncthreads();
#pragma unroll
    for (int kk = 0; kk < 2; ++kk) {
      bf16x8 af[4], bfr[4];
#pragma unroll
      for (int mi = 0; mi < 4; ++mi)
        af[mi] = *(const bf16x8*)(&Al[(wr + mi * 16 + (lane & 15)) * APITCH + kk * 32 + (lane >> 4) * 8]);
#pragma unroll
      for (int ni = 0; ni < 4; ++ni)
        bfr[ni] = *(const bf16x8*)(&Bl[(wc + ni * 16 + (lane & 15)) * APITCH + kk * 32 + (lane >> 4) * 8]);
#pragma unroll
      for (int mi = 0; mi < 4; ++mi)
#pragma unroll
        for (int ni = 0; ni < 4; ++ni)
          acc[mi][ni] = __builtin_amdgcn_mfma_f32_16x16x32_bf16(af[mi], bfr[ni], acc[mi][ni], 0, 0, 0);
    }
    __syncthreads();
  }
  int rq = (lane >> 4) * 4;
#pragma unroll
  for (int mi = 0; mi < 4; ++mi) {
#pragma unroll
    for (int q = 0; q < 4; ++q) {
      int lr = wr + mi * 16 + rq + q;
      int s = mt * 128 + lr;
      if (s < M) {
        int tok = rows[lr];
#pragma unroll
        for (int ni = 0; ni < 4; ++ni) {
          int dcol = dt * 128 + wc + ni * 16 + (lane & 15);
          out[(size_t)tok * DDIM + dcol] = acc[mi][ni][q] + b2[n * DDIM + dcol];
        }
      }
    }
  }
}

// ---------------- passthrough: one wave per row, 1024 blocks ----------------
__global__ __launch_bounds__(256) void passthrough_kernel(
    const float* __restrict__ x, const int* __restrict__ flags,
    float* __restrict__ out) {
  int lane = threadIdx.x & 63;
  int w = threadIdx.x >> 6;
  int base = blockIdx.x * 16;
  for (int r = base + w; r < base + 16; r += 4) {
    if (flags[r]) continue;
    const float4* s = (const float4*)(x + (size_t)r * DDIM);
    float4* d = (float4*)(out + (size_t)r * DDIM);
#pragma unroll
    for (int i = 0; i < 4; ++i) d[lane + i * 64] = s[lane + i * 64];
  }
}

extern "C" void kernel_launch(void* const* d_in, const int* in_sizes, int n_in,
                              void* d_out, int out_size, void* d_ws, size_t ws_size,
                              hipStream_t stream) {
  const float* x  = (const float*)d_in[0];
  const float* Wg = (const float*)d_in[1];
  const float* W1 = (const float*)d_in[2];
  const float* b1 = (const float*)d_in[3];
  const float* W2 = (const float*)d_in[4];
  const float* b2 = (const float*)d_in[5];
  float* out = (float*)d_out;
  char* ws = (char*)d_ws;
  int* counts = (int*)ws;
  int* m_sel  = (int*)(ws + 64);
  int* flags  = (int*)(ws + 128);
  int* e      = (int*)(ws + 128 + 4 * BT);
  float* v    = (float*)(ws + 128 + 8 * BT);
  int* lists  = (int*)(ws + 128 + 12 * BT);

  const size_t MB = 1024 * 1024;
  unsigned short* xb  = (unsigned short*)(ws + 1 * MB);
  unsigned short* w1t = (unsigned short*)(ws + 33 * MB);
  unsigned short* w2t = (unsigned short*)(ws + 97 * MB);
  unsigned short* Hf  = (unsigned short*)(ws + 161 * MB);
  bool fast = ws_size >= 242 * MB;

  zero_meta_kernel<<<1, 64, 0, stream>>>(counts);
  if (fast) {
    prep_kernel<<<256 + 16384, 256, 0, stream>>>(x, Wg, e, v, counts, xb, flags,
                                                 W1, W2, w1t, w2t);
    select_kernel<<<NEXP, 256, 0, stream>>>(e, v, counts, m_sel, lists, flags);
    ffn1_fast<<<NEXP * 10 * 16, 256, 0, stream>>>(xb, w1t, b1, m_sel, lists, Hf);
    ffn2_fast<<<NEXP * 10 * 8, 256, 0, stream>>>(Hf, w2t, b2, m_sel, lists, out);
  } else {
    unsigned short* Hs = (unsigned short*)(ws + 1 * MB);
    gate_kernel<<<BT / 64, 256, 0, stream>>>(x, Wg, e, v, counts, (unsigned short*)nullptr, flags);
    select_kernel<<<NEXP, 256, 0, stream>>>(e, v, counts, m_sel, lists, flags);
    ffn1_slow<<<dim3(HDIM / 128, CAP / 128, NEXP), 256, 0, stream>>>(x, W1, b1, m_sel, lists, Hs);
    ffn2_slow<<<dim3(DDIM / 128, CAP / 128, NEXP), 256, 0, stream>>>(Hs, W2, b2, m_sel, lists, out);
  }
  passthrough_kernel<<<BT / 16, 256, 0, stream>>>(x, flags, out);
}